// Round 1
// baseline (11573.234 us; speedup 1.0000x reference)
//
#include <hip/hip_runtime.h>

// Problem constants
//  A (mps_params): [D=512, d=32, D=512] f32
//  env_L/env_R:    [K=4, 512, w=8, 512] f32
//  coeffs:         [K=4, 8, 8, 5], prefactors: [4], theta: [1]
//  out: scalar f32
//
// out = (1/sum(A^2)) * sum_k pref[k] * sum_{L,v,P,r} Z_k[L,v,P,r] * Y_k[L,P,v,r]
//   Z_k[L,(v,P),r] = sum_{w,p} W2k[(v,P),(w,p)] * T1[L,(w,p),r]
//   T1[(L,w),(p,r)] = env_L[k] @ A          (GEMM 4096x512x16384)
//   Y_k[(L,P),(v,r)] = A @ env_R[k]^layout  (GEMM 16384x512x4096)
//   W2k[(v,P),(w,p)] = sum_c coeffs[k,w,v,c] * ops[c][P,p]

#define BM 64
#define BN 64
#define BK 16

__global__ __launch_bounds__(256) void gemm_f32(
    int M, int N, int Kd,
    const float* __restrict__ A, int lda, long long sA,
    const float* __restrict__ B, int ldb, long long sB,
    float* __restrict__ C, int ldc, long long sC)
{
    long long b = blockIdx.z;
    A += b * sA; B += b * sB; C += b * sC;
    __shared__ float As[BK][BM + 1];
    __shared__ float Bs[BK][BN];
    const int row0 = blockIdx.y * BM;
    const int col0 = blockIdx.x * BN;
    const int tid = threadIdx.x;
    const int tx = tid & 15, ty = tid >> 4;
    float acc[4][4] = {};
    for (int k0 = 0; k0 < Kd; k0 += BK) {
        #pragma unroll
        for (int i = 0; i < 4; ++i) {
            int e = tid + i * 256;
            int ar = e >> 4, ak = e & 15;   // coalesced-ish: 16 consecutive floats per 16 lanes
            As[ak][ar] = A[(long long)(row0 + ar) * lda + (k0 + ak)];
        }
        #pragma unroll
        for (int i = 0; i < 4; ++i) {
            int e = tid + i * 256;
            int bk = e >> 6, bc = e & 63;   // fully coalesced 64-float rows
            Bs[bk][bc] = B[(long long)(k0 + bk) * ldb + (col0 + bc)];
        }
        __syncthreads();
        #pragma unroll
        for (int kk = 0; kk < BK; ++kk) {
            float av[4], bv[4];
            #pragma unroll
            for (int i = 0; i < 4; ++i) av[i] = As[kk][ty * 4 + i];
            #pragma unroll
            for (int j = 0; j < 4; ++j) bv[j] = Bs[kk][tx * 4 + j];
            #pragma unroll
            for (int i = 0; i < 4; ++i)
                #pragma unroll
                for (int j = 0; j < 4; ++j)
                    acc[i][j] += av[i] * bv[j];
        }
        __syncthreads();
    }
    #pragma unroll
    for (int i = 0; i < 4; ++i)
        #pragma unroll
        for (int j = 0; j < 4; ++j)
            C[(long long)(row0 + ty * 4 + i) * ldc + (col0 + tx * 4 + j)] = acc[i][j];
}

__global__ __launch_bounds__(256) void sumsq_kernel(
    const float* __restrict__ A, long long n4, float* __restrict__ out)
{
    const float4* A4 = (const float4*)A;
    float p = 0.f;
    for (long long i = (long long)blockIdx.x * blockDim.x + threadIdx.x; i < n4;
         i += (long long)gridDim.x * blockDim.x) {
        float4 v = A4[i];
        p += v.x * v.x + v.y * v.y + v.z * v.z + v.w * v.w;
    }
    __shared__ float sh[256];
    sh[threadIdx.x] = p;
    __syncthreads();
    for (int s = 128; s > 0; s >>= 1) {
        if (threadIdx.x < s) sh[threadIdx.x] += sh[threadIdx.x + s];
        __syncthreads();
    }
    if (threadIdx.x == 0) atomicAdd(out, sh[0]);
}

// ops[5][32][32]: I, X, P, X@X, P@P
__global__ void build_ops(const float* __restrict__ theta, float* __restrict__ ops)
{
    __shared__ float X[32][32], Pm[32][32];
    int i = threadIdx.y, j = threadIdx.x;
    float c = cosf(theta[0]), s = sinf(theta[0]);
    float aij = (j == i + 1) ? sqrtf((float)j) : 0.f;   // a[i][j]
    float aji = (i == j + 1) ? sqrtf((float)i) : 0.f;   // a[j][i]
    const float inv = 0.70710678118654752440f;
    float x0 = (aij + aji) * inv;
    float p0 = (aij - aji) * inv;
    X[i][j] = c * x0 + s * p0;
    Pm[i][j] = -s * x0 + c * p0;
    __syncthreads();
    float xx = 0.f, pp = 0.f;
    #pragma unroll
    for (int m = 0; m < 32; ++m) {
        xx += X[i][m] * X[m][j];
        pp += Pm[i][m] * Pm[m][j];
    }
    ops[0 * 1024 + i * 32 + j] = (i == j) ? 1.f : 0.f;
    ops[1 * 1024 + i * 32 + j] = X[i][j];
    ops[2 * 1024 + i * 32 + j] = Pm[i][j];
    ops[3 * 1024 + i * 32 + j] = xx;
    ops[4 * 1024 + i * 32 + j] = pp;
}

// W2[k][(v,P),(w,p)] = sum_c coeffs[k,w,v,c] * ops[c][P,p]
__global__ void build_w(const float* __restrict__ coeffs, const float* __restrict__ ops,
                        float* __restrict__ W2)
{
    int b = blockIdx.x;            // (k,w,v)
    int k = b >> 6;
    int w = (b >> 3) & 7;
    int v = b & 7;
    int P = threadIdx.y, p = threadIdx.x;
    const float* cf = coeffs + ((k * 8 + w) * 8 + v) * 5;
    float acc = 0.f;
    #pragma unroll
    for (int c = 0; c < 5; ++c) acc += cf[c] * ops[c * 1024 + P * 32 + p];
    W2[(long long)k * 65536 + (v * 32 + P) * 256 + (w * 32 + p)] = acc;
}

// partial += sum_i Z[i] * Y[perm(i)], i decomposed as (lt, v, P, r)
__global__ __launch_bounds__(256) void dot_kernel(
    const float* __restrict__ Z, const float* __restrict__ Y,
    long long n, float* __restrict__ acc)
{
    float p = 0.f;
    for (long long i = (long long)blockIdx.x * blockDim.x + threadIdx.x; i < n;
         i += (long long)gridDim.x * blockDim.x) {
        long long lt = i >> 17;                 // 131072 elems per lt
        int within = (int)(i & 131071);
        int v = within >> 14;                   // /16384
        int P = (within >> 9) & 31;             // /512 % 32
        int r = within & 511;
        float z = Z[i];                          // [lt, v, P, r]
        float y = Y[lt * 131072 + P * 4096 + v * 512 + r];  // [lt, P, v, r]
        p += z * y;
    }
    __shared__ float sh[256];
    sh[threadIdx.x] = p;
    __syncthreads();
    for (int s = 128; s > 0; s >>= 1) {
        if (threadIdx.x < s) sh[threadIdx.x] += sh[threadIdx.x + s];
        __syncthreads();
    }
    if (threadIdx.x == 0) atomicAdd(acc, sh[0]);
}

__global__ void finalize_kernel(const float* __restrict__ acc, const float* __restrict__ pref,
                                const float* __restrict__ sumsq, float* __restrict__ out)
{
    if (threadIdx.x == 0) {
        float o = 0.f;
        #pragma unroll
        for (int k = 0; k < 4; ++k) o += acc[k] * pref[k];
        out[0] = o / sumsq[0];
    }
}

extern "C" void kernel_launch(void* const* d_in, const int* in_sizes, int n_in,
                              void* d_out, int out_size, void* d_ws, size_t ws_size,
                              hipStream_t stream)
{
    const float* A      = (const float*)d_in[0];  // [512,32,512]
    const float* theta  = (const float*)d_in[1];  // [1]
    const float* envL   = (const float*)d_in[2];  // [4,512,8,512]
    const float* envR   = (const float*)d_in[3];  // [4,512,8,512]
    const float* coeffs = (const float*)d_in[4];  // [4,8,8,5]
    const float* pref   = (const float*)d_in[5];  // [4]
    float* out = (float*)d_out;

    float* ws = (float*)d_ws;
    float* sumsq = ws;           // 1 float
    float* acc   = ws + 4;       // 4 floats
    float* ops   = ws + 64;      // 5120 floats
    float* W2    = ws + 8192;    // 262144 floats (1 MB)
    const size_t base_f = 524288;  // 2 MB offset for big buffers

    // Adaptive L-tile: need 2MB + 3 * Lt * 512KB
    int Lt = 64;
    while (Lt > 8) {
        size_t need = (size_t)base_f * 4 + 3ull * Lt * 131072ull * 4ull;
        if (need <= ws_size) break;
        Lt >>= 1;
    }
    float* T1 = ws + base_f;
    float* Z  = T1 + (size_t)Lt * 131072;
    float* Y  = Z  + (size_t)Lt * 131072;

    hipMemsetAsync(d_ws, 0, 64, stream);  // zero sumsq + acc

    sumsq_kernel<<<2048, 256, 0, stream>>>(A, (long long)in_sizes[0] / 4, sumsq);
    build_ops<<<1, dim3(32, 32), 0, stream>>>(theta, ops);
    build_w<<<256, dim3(32, 32), 0, stream>>>(coeffs, ops, W2);

    const int ntiles = 512 / Lt;
    for (int k = 0; k < 4; ++k) {
        const float* eLk = envL + (size_t)k * 2097152;
        const float* eRk = envR + (size_t)k * 2097152;
        const float* W2k = W2 + (size_t)k * 65536;
        for (int t = 0; t < ntiles; ++t) {
            int Lb = t * Lt;
            // G1: T1[(lt,w),(p,r)] = envL_k[Lb..] @ A   (Lt*8 x 16384 x K512)
            gemm_f32<<<dim3(16384 / BN, (Lt * 8) / BM, 1), 256, 0, stream>>>(
                Lt * 8, 16384, 512,
                eLk + (size_t)Lb * 8 * 512, 512, 0,
                A, 16384, 0,
                T1, 16384, 0);
            // G2: batched per lt: Z_lt[(v,P),r] = W2k @ T1_lt[(w,p),r]  (256x512x256)
            gemm_f32<<<dim3(512 / BN, 256 / BM, Lt), 256, 0, stream>>>(
                256, 512, 256,
                W2k, 256, 0,
                T1, 512, 131072,
                Z, 512, 131072);
            // G3: Y[(lt,P),(v,r)] = A[Lb..] @ envR_k   (Lt*32 x 4096 x K512)
            gemm_f32<<<dim3(4096 / BN, (Lt * 32) / BM, 1), 256, 0, stream>>>(
                Lt * 32, 4096, 512,
                A + (size_t)Lb * 32 * 512, 512, 0,
                eRk, 4096, 0,
                Y, 4096, 0);
            // G4: acc[k] += sum Z * Y(permuted)
            dot_kernel<<<2048, 256, 0, stream>>>(Z, Y, (long long)Lt * 131072, acc + k);
        }
    }
    finalize_kernel<<<1, 64, 0, stream>>>(acc, pref, sumsq, out);
}

// Round 2
// 1696.920 us; speedup vs baseline: 6.8201x; 6.8201x over previous
//
#include <hip/hip_runtime.h>

// SingleSiteMinimizer: out = (1/sum(A^2)) * sum_k pref[k] *
//     sum W[k][w,v,P,p] * T1[L,w,p,r] * Y[L,P,v,r]
// where T1[(L,w),(p,r)] = envL_k @ A      (gemm_bt: envL_k[Lw,l] x At[pr,l])
//       Y[(L,P),(v,r)]  = A @ envR_k      (gemm_bt: A[LP,R]   x envRt[vr,R])
//       M[(w,p),(v,P)]  = sum_{L,r} T1 * Y   (gemm_bt over K=(L,r), 256x256 out)
//       out_k = sum W2[(v,P),(w,p)] * M[(w,p),(v,P)]   (exact f32)

typedef __attribute__((ext_vector_type(8))) short bf16x8;
typedef __attribute__((ext_vector_type(4))) float f32x4;

__device__ __forceinline__ unsigned short f2bf(float f) {
    unsigned u = __float_as_uint(f);
    return (unsigned short)((u + 0x7fffu + ((u >> 16) & 1u)) >> 16);
}

__device__ __forceinline__ void gload16(const void* g, void* l) {
    __builtin_amdgcn_global_load_lds(
        (const __attribute__((address_space(1))) void*)g,
        (__attribute__((address_space(3))) void*)l, 16, 0, 0);
}

// ---------------- m97-style bf16 GEMM: C[M,N] = Aop[M,K] * Bop[N,K]^T ----------------
__global__ __launch_bounds__(256) void gemm_bt(
    int K,
    const unsigned short* __restrict__ Aop, int lda,
    const unsigned short* __restrict__ Bop, int ldb,
    unsigned short* __restrict__ C, int ldc)
{
    __shared__ short As[128 * 32];
    __shared__ short Bs[128 * 32];
    const int tid = threadIdx.x;
    const int wid = tid >> 6, lane = tid & 63;
    const int row0 = blockIdx.y * 128, col0 = blockIdx.x * 128;
    const int wr = (wid >> 1) * 64, wc = (wid & 1) * 64;
    const int lrow = lane & 15, kb = (lane >> 4) * 8;

    const int c0 = tid, c1 = tid + 256;
    const int r0c = c0 >> 2, k0c = (c0 & 3) * 8;
    const int r1c = c1 >> 2, k1c = (c1 & 3) * 8;

    f32x4 acc[4][4] = {};

    for (int k0 = 0; k0 < K; k0 += 32) {
        gload16(Aop + (size_t)(row0 + r0c) * lda + k0 + k0c, (short*)As + c0 * 8);
        gload16(Aop + (size_t)(row0 + r1c) * lda + k0 + k1c, (short*)As + c1 * 8);
        gload16(Bop + (size_t)(col0 + r0c) * ldb + k0 + k0c, (short*)Bs + c0 * 8);
        gload16(Bop + (size_t)(col0 + r1c) * ldb + k0 + k1c, (short*)Bs + c1 * 8);
        __syncthreads();
        bf16x8 a[4], b[4];
        #pragma unroll
        for (int i = 0; i < 4; ++i)
            a[i] = *(const bf16x8*)&As[(wr + i * 16 + lrow) * 32 + kb];
        #pragma unroll
        for (int j = 0; j < 4; ++j)
            b[j] = *(const bf16x8*)&Bs[(wc + j * 16 + lrow) * 32 + kb];
        #pragma unroll
        for (int i = 0; i < 4; ++i)
            #pragma unroll
            for (int j = 0; j < 4; ++j)
                acc[i][j] = __builtin_amdgcn_mfma_f32_16x16x32_bf16(a[i], b[j], acc[i][j], 0, 0, 0);
        __syncthreads();
    }

    const int orow = (lane >> 4) * 4, ocol = lane & 15;
    #pragma unroll
    for (int i = 0; i < 4; ++i)
        #pragma unroll
        for (int j = 0; j < 4; ++j)
            #pragma unroll
            for (int q = 0; q < 4; ++q) {
                int r = row0 + wr + i * 16 + orow + q;
                int c = col0 + wc + j * 16 + ocol;
                C[(size_t)r * ldc + c] = f2bf(acc[i][j][q]);
            }
}

// ---------------- G4: M[(w,p),(v,P)] += sum_{(lt,r)} T1view * Yview ----------------
// T1[(lt*8+w)*16384 + p*512 + r], Y[(lt*32+P)*4096 + v*512 + r]; kk = lt*512 + r
__global__ __launch_bounds__(256) void gemm_g4(
    const unsigned short* __restrict__ T1, const unsigned short* __restrict__ Y,
    float* __restrict__ Mout, int BKC)
{
    __shared__ short As[128 * 32];
    __shared__ short Bs[128 * 32];
    const int tid = threadIdx.x;
    const int wid = tid >> 6, lane = tid & 63;
    const int m0 = blockIdx.x * 128, n0 = blockIdx.y * 128;
    const int kz = blockIdx.z * BKC;
    const int wr = (wid >> 1) * 64, wc = (wid & 1) * 64;
    const int lrow = lane & 15, kb = (lane >> 4) * 8;

    const int c0 = tid, c1 = tid + 256;
    const int mA0 = m0 + (c0 >> 2), kA0 = (c0 & 3) * 8;
    const int mA1 = m0 + (c1 >> 2), kA1 = (c1 & 3) * 8;
    const int nB0 = n0 + (c0 >> 2), nB1 = n0 + (c1 >> 2);

    f32x4 acc[4][4] = {};

    for (int k0 = 0; k0 < BKC; k0 += 32) {
        const int kk = kz + k0;
        const size_t ltoff = (size_t)(kk >> 9) * 131072;
        const int rr = kk & 511;
        gload16(T1 + ltoff + (mA0 >> 5) * 16384 + (mA0 & 31) * 512 + rr + kA0, (short*)As + c0 * 8);
        gload16(T1 + ltoff + (mA1 >> 5) * 16384 + (mA1 & 31) * 512 + rr + kA1, (short*)As + c1 * 8);
        gload16(Y + ltoff + (nB0 & 31) * 4096 + (nB0 >> 5) * 512 + rr + kA0, (short*)Bs + c0 * 8);
        gload16(Y + ltoff + (nB1 & 31) * 4096 + (nB1 >> 5) * 512 + rr + kA1, (short*)Bs + c1 * 8);
        __syncthreads();
        bf16x8 a[4], b[4];
        #pragma unroll
        for (int i = 0; i < 4; ++i)
            a[i] = *(const bf16x8*)&As[(wr + i * 16 + lrow) * 32 + kb];
        #pragma unroll
        for (int j = 0; j < 4; ++j)
            b[j] = *(const bf16x8*)&Bs[(wc + j * 16 + lrow) * 32 + kb];
        #pragma unroll
        for (int i = 0; i < 4; ++i)
            #pragma unroll
            for (int j = 0; j < 4; ++j)
                acc[i][j] = __builtin_amdgcn_mfma_f32_16x16x32_bf16(a[i], b[j], acc[i][j], 0, 0, 0);
        __syncthreads();
    }

    const int orow = (lane >> 4) * 4, ocol = lane & 15;
    #pragma unroll
    for (int i = 0; i < 4; ++i)
        #pragma unroll
        for (int j = 0; j < 4; ++j)
            #pragma unroll
            for (int q = 0; q < 4; ++q) {
                int m = m0 + wr + i * 16 + orow + q;
                int n = n0 + wc + j * 16 + ocol;
                atomicAdd(&Mout[(size_t)m * 256 + n], acc[i][j][q]);
            }
}

// ---------------- helpers ----------------
__global__ __launch_bounds__(256) void sumsq_kernel(
    const float* __restrict__ A, long long n4, float* __restrict__ out)
{
    const float4* A4 = (const float4*)A;
    float p = 0.f;
    for (long long i = (long long)blockIdx.x * blockDim.x + threadIdx.x; i < n4;
         i += (long long)gridDim.x * blockDim.x) {
        float4 v = A4[i];
        p += v.x * v.x + v.y * v.y + v.z * v.z + v.w * v.w;
    }
    __shared__ float sh[256];
    sh[threadIdx.x] = p;
    __syncthreads();
    for (int s = 128; s > 0; s >>= 1) {
        if (threadIdx.x < s) sh[threadIdx.x] += sh[threadIdx.x + s];
        __syncthreads();
    }
    if (threadIdx.x == 0) atomicAdd(out, sh[0]);
}

__global__ void cast_kernel(const float* __restrict__ in, unsigned short* __restrict__ out,
                            long long n4)
{
    for (long long i = (long long)blockIdx.x * blockDim.x + threadIdx.x; i < n4;
         i += (long long)gridDim.x * blockDim.x) {
        float4 v = ((const float4*)in)[i];
        union { unsigned short s[4]; uint2 d; } o;
        o.s[0] = f2bf(v.x); o.s[1] = f2bf(v.y); o.s[2] = f2bf(v.z); o.s[3] = f2bf(v.w);
        ((uint2*)out)[i] = o.d;
    }
}

__global__ void transpose_cast(const float* __restrict__ in, unsigned short* __restrict__ out,
                               int R, int C, long long in_stride, long long out_stride)
{
    __shared__ float tile[32][33];
    in += (long long)blockIdx.z * in_stride;
    out += (long long)blockIdx.z * out_stride;
    int c0 = blockIdx.x * 32, r0 = blockIdx.y * 32;
    int tx = threadIdx.x, ty = threadIdx.y;  // (32, 8)
    #pragma unroll
    for (int i = 0; i < 4; ++i)
        tile[ty + i * 8][tx] = in[(size_t)(r0 + ty + i * 8) * C + c0 + tx];
    __syncthreads();
    #pragma unroll
    for (int i = 0; i < 4; ++i)
        out[(size_t)(c0 + ty + i * 8) * R + r0 + tx] = f2bf(tile[tx][ty + i * 8]);
}

__global__ void build_ops(const float* __restrict__ theta, float* __restrict__ ops)
{
    __shared__ float X[32][32], Pm[32][32];
    int i = threadIdx.y, j = threadIdx.x;
    float c = cosf(theta[0]), s = sinf(theta[0]);
    float aij = (j == i + 1) ? sqrtf((float)j) : 0.f;
    float aji = (i == j + 1) ? sqrtf((float)i) : 0.f;
    const float inv = 0.70710678118654752440f;
    float x0 = (aij + aji) * inv;
    float p0 = (aij - aji) * inv;
    X[i][j] = c * x0 + s * p0;
    Pm[i][j] = -s * x0 + c * p0;
    __syncthreads();
    float xx = 0.f, pp = 0.f;
    #pragma unroll
    for (int m = 0; m < 32; ++m) {
        xx += X[i][m] * X[m][j];
        pp += Pm[i][m] * Pm[m][j];
    }
    ops[0 * 1024 + i * 32 + j] = (i == j) ? 1.f : 0.f;
    ops[1 * 1024 + i * 32 + j] = X[i][j];
    ops[2 * 1024 + i * 32 + j] = Pm[i][j];
    ops[3 * 1024 + i * 32 + j] = xx;
    ops[4 * 1024 + i * 32 + j] = pp;
}

// W2[k][(v*32+P)*256 + (w*32+p)] = sum_c coeffs[k,w,v,c] * ops[c][P,p]
__global__ void build_w(const float* __restrict__ coeffs, const float* __restrict__ ops,
                        float* __restrict__ W2)
{
    int b = blockIdx.x;  // (k,w,v)
    int k = b >> 6, w = (b >> 3) & 7, v = b & 7;
    int P = threadIdx.y, p = threadIdx.x;
    const float* cf = coeffs + ((k * 8 + w) * 8 + v) * 5;
    float acc = 0.f;
    #pragma unroll
    for (int c = 0; c < 5; ++c) acc += cf[c] * ops[c * 1024 + P * 32 + p];
    W2[(size_t)k * 65536 + (v * 32 + P) * 256 + (w * 32 + p)] = acc;
}

__global__ __launch_bounds__(256) void final_reduce(
    const float* __restrict__ M256, const float* __restrict__ W2,
    const float* __restrict__ pref, const float* __restrict__ sumsq,
    float* __restrict__ out)
{
    float p = 0.f;
    for (int k = 0; k < 4; ++k) {
        const float* Mk = M256 + (size_t)k * 65536;
        const float* Wk = W2 + (size_t)k * 65536;
        float pk = 0.f;
        for (int i = threadIdx.x; i < 65536; i += 256) {
            int m = i >> 8, n = i & 255;
            pk += Mk[i] * Wk[n * 256 + m];
        }
        p += pk * pref[k];
    }
    __shared__ float sh[256];
    sh[threadIdx.x] = p;
    __syncthreads();
    for (int s = 128; s > 0; s >>= 1) {
        if (threadIdx.x < s) sh[threadIdx.x] += sh[threadIdx.x + s];
        __syncthreads();
    }
    if (threadIdx.x == 0) out[0] = sh[0] / sumsq[0];
}

extern "C" void kernel_launch(void* const* d_in, const int* in_sizes, int n_in,
                              void* d_out, int out_size, void* d_ws, size_t ws_size,
                              hipStream_t stream)
{
    const float* A      = (const float*)d_in[0];  // [512,32,512]
    const float* theta  = (const float*)d_in[1];
    const float* envL   = (const float*)d_in[2];  // [4,512,8,512]
    const float* envR   = (const float*)d_in[3];  // [4,512,8,512]
    const float* coeffs = (const float*)d_in[4];  // [4,8,8,5]
    const float* pref   = (const float*)d_in[5];  // [4]
    float* out = (float*)d_out;

    char* ws = (char*)d_ws;
    float* sumsq = (float*)ws;                                 // 4 B
    float* ops   = (float*)(ws + 64);                          // 20 KB
    float* W2    = (float*)(ws + (32 << 10));                  // 1 MB
    float* M256  = (float*)(ws + ((3ull << 20) / 2));          // 1 MB at 1.5MB
    unsigned short* envLbf  = (unsigned short*)(ws + (4ull << 20));   // 16.8 MB
    unsigned short* Abf     = (unsigned short*)(ws + (21ull << 20));  // 16.8 MB
    unsigned short* Atbf    = (unsigned short*)(ws + (38ull << 20));  // 16.8 MB
    unsigned short* envRtbf = (unsigned short*)(ws + (55ull << 20));  // 16.8 MB
    const size_t big0 = 72ull << 20;

    int Lt = 512;
    while (Lt > 32) {
        size_t need = big0 + 2ull * (size_t)Lt * 262144ull;  // T1 + Y bytes
        if (need <= ws_size) break;
        Lt >>= 1;
    }
    unsigned short* T1 = (unsigned short*)(ws + big0);
    unsigned short* Yb = T1 + (size_t)Lt * 131072;  // shorts

    hipMemsetAsync(ws, 0, 64, stream);
    hipMemsetAsync(M256, 0, 1 << 20, stream);

    sumsq_kernel<<<1024, 256, 0, stream>>>(A, 2097152LL, sumsq);
    build_ops<<<1, dim3(32, 32), 0, stream>>>(theta, ops);
    build_w<<<256, dim3(32, 32), 0, stream>>>(coeffs, ops, W2);
    cast_kernel<<<2048, 256, 0, stream>>>(A, Abf, 2097152LL);
    cast_kernel<<<2048, 256, 0, stream>>>(envL, envLbf, 2097152LL);
    transpose_cast<<<dim3(512, 16, 1), dim3(32, 8), 0, stream>>>(A, Atbf, 512, 16384, 0, 0);
    transpose_cast<<<dim3(128, 16, 4), dim3(32, 8), 0, stream>>>(envR, envRtbf, 512, 4096,
                                                                 2097152LL, 2097152LL);

    const int ntiles = 512 / Lt;
    const int KT = Lt * 512;
    int BKC = KT / 64; if (BKC < 512) BKC = 512;
    const int zk = KT / BKC;

    for (int t = 0; t < ntiles; ++t) {
        for (int k = 0; k < 4; ++k) {
            const unsigned short* eL  = envLbf + (size_t)k * 2097152 + (size_t)t * Lt * 4096;
            const unsigned short* eRt = envRtbf + (size_t)k * 2097152;
            // T1[(lt,w),(p,r)] = envL_tile x At^T   [M=Lt*8, N=16384, K=512]
            gemm_bt<<<dim3(128, Lt * 8 / 128), 256, 0, stream>>>(
                512, eL, 512, Atbf, 512, T1, 16384);
            // Y[(lt,P),(v,r)] = A_tile x envRt^T    [M=Lt*32, N=4096, K=512]
            gemm_bt<<<dim3(32, Lt * 32 / 128), 256, 0, stream>>>(
                512, Abf + (size_t)t * Lt * 16384, 512, eRt, 512, Yb, 4096);
            // M[(w,p),(v,P)] += T1view x Yview^T    [256 x 256 x Lt*512]
            gemm_g4<<<dim3(2, 2, zk), 256, 0, stream>>>(T1, Yb, M256 + (size_t)k * 65536, BKC);
        }
    }
    final_reduce<<<1, 256, 0, stream>>>(M256, W2, pref, sumsq, out);
}

// Round 3
// 1438.627 us; speedup vs baseline: 8.0446x; 1.1795x over previous
//
#include <hip/hip_runtime.h>

// SingleSiteMinimizer: out = (1/sum(A^2)) * sum_k pref[k] *
//     sum W[k][w,v,P,p] * T1[L,w,p,r] * Y[L,P,v,r]
// where T1[(L,w),(p,r)] = envL_k @ A      (gemm_bt: envL_k[Lw,l] x At[pr,l])
//       Y[(L,P),(v,r)]  = A @ envR_k      (gemm_bt: A[LP,R]   x envRt[vr,R])
//       M[(w,p),(v,P)]  = sum_{L,r} T1 * Y   (gemm_bt over K=(L,r), 256x256 out)
//       out_k = sum W2[(v,P),(w,p)] * M[(w,p),(v,P)]   (exact f32)
// All MFMA operands fp16 (10-bit mantissa) for accuracy margin; accum f32.

typedef __attribute__((ext_vector_type(8))) _Float16 f16x8;
typedef __attribute__((ext_vector_type(4))) float f32x4;

__device__ __forceinline__ unsigned short f2h(float f) {
    _Float16 h = (_Float16)f;
    return *(unsigned short*)&h;
}

__device__ __forceinline__ void gload16(const void* g, void* l) {
    __builtin_amdgcn_global_load_lds(
        (const __attribute__((address_space(1))) void*)g,
        (__attribute__((address_space(3))) void*)l, 16, 0, 0);
}

// ---------------- m97-style fp16 GEMM: C[M,N] = Aop[M,K] * Bop[N,K]^T ----------------
__global__ __launch_bounds__(256) void gemm_bt(
    int K,
    const unsigned short* __restrict__ Aop, int lda,
    const unsigned short* __restrict__ Bop, int ldb,
    unsigned short* __restrict__ C, int ldc)
{
    __shared__ short As[128 * 32];
    __shared__ short Bs[128 * 32];
    const int tid = threadIdx.x;
    const int wid = tid >> 6, lane = tid & 63;
    const int row0 = blockIdx.y * 128, col0 = blockIdx.x * 128;
    const int wr = (wid >> 1) * 64, wc = (wid & 1) * 64;
    const int lrow = lane & 15, kb = (lane >> 4) * 8;

    const int c0 = tid, c1 = tid + 256;
    const int r0c = c0 >> 2, k0c = (c0 & 3) * 8;
    const int r1c = c1 >> 2, k1c = (c1 & 3) * 8;

    f32x4 acc[4][4] = {};

    for (int k0 = 0; k0 < K; k0 += 32) {
        gload16(Aop + (size_t)(row0 + r0c) * lda + k0 + k0c, (short*)As + c0 * 8);
        gload16(Aop + (size_t)(row0 + r1c) * lda + k0 + k1c, (short*)As + c1 * 8);
        gload16(Bop + (size_t)(col0 + r0c) * ldb + k0 + k0c, (short*)Bs + c0 * 8);
        gload16(Bop + (size_t)(col0 + r1c) * ldb + k0 + k1c, (short*)Bs + c1 * 8);
        __syncthreads();
        f16x8 a[4], b[4];
        #pragma unroll
        for (int i = 0; i < 4; ++i)
            a[i] = *(const f16x8*)&As[(wr + i * 16 + lrow) * 32 + kb];
        #pragma unroll
        for (int j = 0; j < 4; ++j)
            b[j] = *(const f16x8*)&Bs[(wc + j * 16 + lrow) * 32 + kb];
        #pragma unroll
        for (int i = 0; i < 4; ++i)
            #pragma unroll
            for (int j = 0; j < 4; ++j)
                acc[i][j] = __builtin_amdgcn_mfma_f32_16x16x32_f16(a[i], b[j], acc[i][j], 0, 0, 0);
        __syncthreads();
    }

    const int orow = (lane >> 4) * 4, ocol = lane & 15;
    #pragma unroll
    for (int i = 0; i < 4; ++i)
        #pragma unroll
        for (int j = 0; j < 4; ++j)
            #pragma unroll
            for (int q = 0; q < 4; ++q) {
                int r = row0 + wr + i * 16 + orow + q;
                int c = col0 + wc + j * 16 + ocol;
                C[(size_t)r * ldc + c] = f2h(acc[i][j][q]);
            }
}

// ---------------- G4: M[(w,p),(v,P)] += sum_{(lt,r)} T1view * Yview ----------------
// T1[(lt*8+w)*16384 + p*512 + r], Y[(lt*32+P)*4096 + v*512 + r]; kk = lt*512 + r
__global__ __launch_bounds__(256) void gemm_g4(
    const unsigned short* __restrict__ T1, const unsigned short* __restrict__ Y,
    float* __restrict__ Mout, int BKC)
{
    __shared__ short As[128 * 32];
    __shared__ short Bs[128 * 32];
    const int tid = threadIdx.x;
    const int wid = tid >> 6, lane = tid & 63;
    const int m0 = blockIdx.x * 128, n0 = blockIdx.y * 128;
    const int kz = blockIdx.z * BKC;
    const int wr = (wid >> 1) * 64, wc = (wid & 1) * 64;
    const int lrow = lane & 15, kb = (lane >> 4) * 8;

    const int c0 = tid, c1 = tid + 256;
    const int mA0 = m0 + (c0 >> 2), kA0 = (c0 & 3) * 8;
    const int mA1 = m0 + (c1 >> 2), kA1 = (c1 & 3) * 8;
    const int nB0 = n0 + (c0 >> 2), nB1 = n0 + (c1 >> 2);

    f32x4 acc[4][4] = {};

    for (int k0 = 0; k0 < BKC; k0 += 32) {
        const int kk = kz + k0;
        const size_t ltoff = (size_t)(kk >> 9) * 131072;
        const int rr = kk & 511;
        gload16(T1 + ltoff + (mA0 >> 5) * 16384 + (mA0 & 31) * 512 + rr + kA0, (short*)As + c0 * 8);
        gload16(T1 + ltoff + (mA1 >> 5) * 16384 + (mA1 & 31) * 512 + rr + kA1, (short*)As + c1 * 8);
        gload16(Y + ltoff + (nB0 & 31) * 4096 + (nB0 >> 5) * 512 + rr + kA0, (short*)Bs + c0 * 8);
        gload16(Y + ltoff + (nB1 & 31) * 4096 + (nB1 >> 5) * 512 + rr + kA1, (short*)Bs + c1 * 8);
        __syncthreads();
        f16x8 a[4], b[4];
        #pragma unroll
        for (int i = 0; i < 4; ++i)
            a[i] = *(const f16x8*)&As[(wr + i * 16 + lrow) * 32 + kb];
        #pragma unroll
        for (int j = 0; j < 4; ++j)
            b[j] = *(const f16x8*)&Bs[(wc + j * 16 + lrow) * 32 + kb];
        #pragma unroll
        for (int i = 0; i < 4; ++i)
            #pragma unroll
            for (int j = 0; j < 4; ++j)
                acc[i][j] = __builtin_amdgcn_mfma_f32_16x16x32_f16(a[i], b[j], acc[i][j], 0, 0, 0);
        __syncthreads();
    }

    const int orow = (lane >> 4) * 4, ocol = lane & 15;
    #pragma unroll
    for (int i = 0; i < 4; ++i)
        #pragma unroll
        for (int j = 0; j < 4; ++j)
            #pragma unroll
            for (int q = 0; q < 4; ++q) {
                int m = m0 + wr + i * 16 + orow + q;
                int n = n0 + wc + j * 16 + ocol;
                atomicAdd(&Mout[(size_t)m * 256 + n], acc[i][j][q]);
            }
}

// ---------------- helpers ----------------
__global__ __launch_bounds__(256) void sumsq_kernel(
    const float* __restrict__ A, long long n4, float* __restrict__ out)
{
    const float4* A4 = (const float4*)A;
    float p = 0.f;
    for (long long i = (long long)blockIdx.x * blockDim.x + threadIdx.x; i < n4;
         i += (long long)gridDim.x * blockDim.x) {
        float4 v = A4[i];
        p += v.x * v.x + v.y * v.y + v.z * v.z + v.w * v.w;
    }
    __shared__ float sh[256];
    sh[threadIdx.x] = p;
    __syncthreads();
    for (int s = 128; s > 0; s >>= 1) {
        if (threadIdx.x < s) sh[threadIdx.x] += sh[threadIdx.x + s];
        __syncthreads();
    }
    if (threadIdx.x == 0) atomicAdd(out, sh[0]);
}

__global__ void cast_kernel(const float* __restrict__ in, unsigned short* __restrict__ out,
                            long long n4)
{
    for (long long i = (long long)blockIdx.x * blockDim.x + threadIdx.x; i < n4;
         i += (long long)gridDim.x * blockDim.x) {
        float4 v = ((const float4*)in)[i];
        union { unsigned short s[4]; uint2 d; } o;
        o.s[0] = f2h(v.x); o.s[1] = f2h(v.y); o.s[2] = f2h(v.z); o.s[3] = f2h(v.w);
        ((uint2*)out)[i] = o.d;
    }
}

__global__ void transpose_cast(const float* __restrict__ in, unsigned short* __restrict__ out,
                               int R, int C, long long in_stride, long long out_stride)
{
    __shared__ float tile[32][33];
    in += (long long)blockIdx.z * in_stride;
    out += (long long)blockIdx.z * out_stride;
    int c0 = blockIdx.x * 32, r0 = blockIdx.y * 32;
    int tx = threadIdx.x, ty = threadIdx.y;  // (32, 8)
    #pragma unroll
    for (int i = 0; i < 4; ++i)
        tile[ty + i * 8][tx] = in[(size_t)(r0 + ty + i * 8) * C + c0 + tx];
    __syncthreads();
    #pragma unroll
    for (int i = 0; i < 4; ++i)
        out[(size_t)(c0 + ty + i * 8) * R + r0 + tx] = f2h(tile[tx][ty + i * 8]);
}

__global__ void build_ops(const float* __restrict__ theta, float* __restrict__ ops)
{
    __shared__ float X[32][32], Pm[32][32];
    int i = threadIdx.y, j = threadIdx.x;
    float c = cosf(theta[0]), s = sinf(theta[0]);
    float aij = (j == i + 1) ? sqrtf((float)j) : 0.f;
    float aji = (i == j + 1) ? sqrtf((float)i) : 0.f;
    const float inv = 0.70710678118654752440f;
    float x0 = (aij + aji) * inv;
    float p0 = (aij - aji) * inv;
    X[i][j] = c * x0 + s * p0;
    Pm[i][j] = -s * x0 + c * p0;
    __syncthreads();
    float xx = 0.f, pp = 0.f;
    #pragma unroll
    for (int m = 0; m < 32; ++m) {
        xx += X[i][m] * X[m][j];
        pp += Pm[i][m] * Pm[m][j];
    }
    ops[0 * 1024 + i * 32 + j] = (i == j) ? 1.f : 0.f;
    ops[1 * 1024 + i * 32 + j] = X[i][j];
    ops[2 * 1024 + i * 32 + j] = Pm[i][j];
    ops[3 * 1024 + i * 32 + j] = xx;
    ops[4 * 1024 + i * 32 + j] = pp;
}

// W2[k][(v*32+P)*256 + (w*32+p)] = sum_c coeffs[k,w,v,c] * ops[c][P,p]
__global__ void build_w(const float* __restrict__ coeffs, const float* __restrict__ ops,
                        float* __restrict__ W2)
{
    int b = blockIdx.x;  // (k,w,v)
    int k = b >> 6, w = (b >> 3) & 7, v = b & 7;
    int P = threadIdx.y, p = threadIdx.x;
    const float* cf = coeffs + ((k * 8 + w) * 8 + v) * 5;
    float acc = 0.f;
    #pragma unroll
    for (int c = 0; c < 5; ++c) acc += cf[c] * ops[c * 1024 + P * 32 + p];
    W2[(size_t)k * 65536 + (v * 32 + P) * 256 + (w * 32 + p)] = acc;
}

// out_partial += sum over all (k,m,n) of pref[k] * M[k,m,n] * W2[k,n,m]
__global__ __launch_bounds__(256) void dotWM_kernel(
    const float* __restrict__ M256, const float* __restrict__ W2,
    const float* __restrict__ pref, float* __restrict__ acc)
{
    float p = 0.f;
    for (int i = blockIdx.x * 256 + threadIdx.x; i < 262144; i += gridDim.x * 256) {
        int k = i >> 16, m = (i >> 8) & 255, n = i & 255;
        p += pref[k] * M256[i] * W2[(k << 16) + n * 256 + m];
    }
    __shared__ float sh[256];
    sh[threadIdx.x] = p;
    __syncthreads();
    for (int s = 128; s > 0; s >>= 1) {
        if (threadIdx.x < s) sh[threadIdx.x] += sh[threadIdx.x + s];
        __syncthreads();
    }
    if (threadIdx.x == 0) atomicAdd(acc, sh[0]);
}

__global__ void finalize_kernel(const float* __restrict__ acc, const float* __restrict__ sumsq,
                                float* __restrict__ out)
{
    if (threadIdx.x == 0) out[0] = acc[0] / sumsq[0];
}

extern "C" void kernel_launch(void* const* d_in, const int* in_sizes, int n_in,
                              void* d_out, int out_size, void* d_ws, size_t ws_size,
                              hipStream_t stream)
{
    const float* A      = (const float*)d_in[0];  // [512,32,512]
    const float* theta  = (const float*)d_in[1];
    const float* envL   = (const float*)d_in[2];  // [4,512,8,512]
    const float* envR   = (const float*)d_in[3];  // [4,512,8,512]
    const float* coeffs = (const float*)d_in[4];  // [4,8,8,5]
    const float* pref   = (const float*)d_in[5];  // [4]
    float* out = (float*)d_out;

    char* ws = (char*)d_ws;
    float* sumsq = (float*)ws;                                 // 4 B
    float* dacc  = (float*)(ws + 4);                           // 4 B
    float* ops   = (float*)(ws + 64);                          // 20 KB
    float* W2    = (float*)(ws + (32 << 10));                  // 1 MB
    float* M256  = (float*)(ws + ((3ull << 20) / 2));          // 1 MB at 1.5MB
    unsigned short* envLh  = (unsigned short*)(ws + (4ull << 20));   // 16.8 MB
    unsigned short* Ah     = (unsigned short*)(ws + (21ull << 20));  // 16.8 MB
    unsigned short* Ath    = (unsigned short*)(ws + (38ull << 20));  // 16.8 MB
    unsigned short* envRth = (unsigned short*)(ws + (55ull << 20));  // 16.8 MB
    const size_t big0 = 72ull << 20;

    int Lt = 512;
    while (Lt > 32) {
        size_t need = big0 + 2ull * (size_t)Lt * 262144ull;  // T1 + Y bytes
        if (need <= ws_size) break;
        Lt >>= 1;
    }
    unsigned short* T1 = (unsigned short*)(ws + big0);
    unsigned short* Yb = T1 + (size_t)Lt * 131072;  // shorts

    hipMemsetAsync(ws, 0, 64, stream);
    hipMemsetAsync(M256, 0, 1 << 20, stream);

    sumsq_kernel<<<1024, 256, 0, stream>>>(A, 2097152LL, sumsq);
    build_ops<<<1, dim3(32, 32), 0, stream>>>(theta, ops);
    build_w<<<256, dim3(32, 32), 0, stream>>>(coeffs, ops, W2);
    cast_kernel<<<2048, 256, 0, stream>>>(A, Ah, 2097152LL);
    cast_kernel<<<2048, 256, 0, stream>>>(envL, envLh, 2097152LL);
    transpose_cast<<<dim3(512, 16, 1), dim3(32, 8), 0, stream>>>(A, Ath, 512, 16384, 0, 0);
    transpose_cast<<<dim3(128, 16, 4), dim3(32, 8), 0, stream>>>(envR, envRth, 512, 4096,
                                                                 2097152LL, 2097152LL);

    const int ntiles = 512 / Lt;
    const int KT = Lt * 512;
    int BKC = KT / 64; if (BKC < 512) BKC = 512;
    const int zk = KT / BKC;

    for (int t = 0; t < ntiles; ++t) {
        for (int k = 0; k < 4; ++k) {
            const unsigned short* eL  = envLh + (size_t)k * 2097152 + (size_t)t * Lt * 4096;
            const unsigned short* eRt = envRth + (size_t)k * 2097152;
            // T1[(lt,w),(p,r)] = envL_tile x At^T   [M=Lt*8, N=16384, K=512]
            gemm_bt<<<dim3(128, Lt * 8 / 128), 256, 0, stream>>>(
                512, eL, 512, Ath, 512, T1, 16384);
            // Y[(lt,P),(v,r)] = A_tile x envRt^T    [M=Lt*32, N=4096, K=512]
            gemm_bt<<<dim3(32, Lt * 32 / 128), 256, 0, stream>>>(
                512, Ah + (size_t)t * Lt * 16384, 512, eRt, 512, Yb, 4096);
            // M[(w,p),(v,P)] += T1view x Yview^T    [256 x 256 x Lt*512]
            gemm_g4<<<dim3(2, 2, zk), 256, 0, stream>>>(T1, Yb, M256 + (size_t)k * 65536, BKC);
        }
    }
    dotWM_kernel<<<256, 256, 0, stream>>>(M256, W2, pref, dacc);
    finalize_kernel<<<1, 64, 0, stream>>>(dacc, sumsq, out);
}

// Round 4
// 1437.431 us; speedup vs baseline: 8.0513x; 1.0008x over previous
//
#include <hip/hip_runtime.h>

// SingleSiteMinimizer, fp16-MFMA pipeline:
//   T1[k][(lt,w)][(p,r)] = envL_k(tile) @ A        (gemm_bt2, A-side k-mapped)
//   Y'[(lt,P)][k*4096+(v,r)] = A(tile) @ envR_k^T  (gemm_bt2, k in N dim)
//   out += sum_k sum_{m,n} (T1_k Y_k^T)[m,n] * W2pref[k][n][m]   (gemm_g4_tr, fused trace)
//   out /= sum(A^2)

typedef __attribute__((ext_vector_type(8))) _Float16 f16x8;
typedef __attribute__((ext_vector_type(4))) float f32x4;

__device__ __forceinline__ unsigned short f2h(float f) {
    _Float16 h = (_Float16)f;
    return *(unsigned short*)&h;
}

__device__ __forceinline__ void gload16(const void* g, void* l) {
    __builtin_amdgcn_global_load_lds(
        (const __attribute__((address_space(1))) void*)g,
        (__attribute__((address_space(3))) void*)l, 16, 0, 0);
}

// ---------- fp16 GEMM C[M,N] = Aop[M,K] x Bop[N,K]^T, A rows k-slab-mapped ----------
// A row gr address: Abase + gr*lda + (gr>>kshiftA)*kextraA
__global__ __launch_bounds__(256) void gemm_bt2(
    int K,
    const unsigned short* __restrict__ Aop, int lda, int kshiftA, long long kextraA,
    const unsigned short* __restrict__ Bop, int ldb,
    unsigned short* __restrict__ C, int ldc)
{
    __shared__ short As[4096];
    __shared__ short Bs[4096];
    const int tid = threadIdx.x;
    const int wid = tid >> 6, lane = tid & 63;
    const int row0 = blockIdx.y * 128, col0 = blockIdx.x * 128;
    const int wr = (wid >> 1) * 64, wc = (wid & 1) * 64;
    const int lrow = lane & 15, kb = (lane >> 4) * 8;

    const int c0 = tid, c1 = tid + 256;
    const int r0 = c0 >> 2, kc0 = (c0 & 3) * 8;
    const int r1 = c1 >> 2, kc1 = (c1 & 3) * 8;
    const int gr0 = row0 + r0, gr1 = row0 + r1;
    const size_t aoff0 = (size_t)gr0 * lda + (size_t)((unsigned)gr0 >> kshiftA) * kextraA;
    const size_t aoff1 = (size_t)gr1 * lda + (size_t)((unsigned)gr1 >> kshiftA) * kextraA;
    const size_t boff0 = (size_t)(col0 + r0) * ldb;
    const size_t boff1 = (size_t)(col0 + r1) * ldb;

    f32x4 acc[4][4] = {};

    for (int k0 = 0; k0 < K; k0 += 32) {
        gload16(Aop + aoff0 + k0 + kc0, (short*)As + c0 * 8);
        gload16(Aop + aoff1 + k0 + kc1, (short*)As + c1 * 8);
        gload16(Bop + boff0 + k0 + kc0, (short*)Bs + c0 * 8);
        gload16(Bop + boff1 + k0 + kc1, (short*)Bs + c1 * 8);
        __syncthreads();
        f16x8 a[4], b[4];
        #pragma unroll
        for (int i = 0; i < 4; ++i)
            a[i] = *(const f16x8*)&As[(wr + i * 16 + lrow) * 32 + kb];
        #pragma unroll
        for (int j = 0; j < 4; ++j)
            b[j] = *(const f16x8*)&Bs[(wc + j * 16 + lrow) * 32 + kb];
        #pragma unroll
        for (int i = 0; i < 4; ++i)
            #pragma unroll
            for (int j = 0; j < 4; ++j)
                acc[i][j] = __builtin_amdgcn_mfma_f32_16x16x32_f16(a[i], b[j], acc[i][j], 0, 0, 0);
        __syncthreads();
    }

    const int orow = (lane >> 4) * 4, ocol = lane & 15;
    #pragma unroll
    for (int i = 0; i < 4; ++i)
        #pragma unroll
        for (int j = 0; j < 4; ++j)
            #pragma unroll
            for (int q = 0; q < 4; ++q) {
                int r = row0 + wr + i * 16 + orow + q;
                int c = col0 + wc + j * 16 + ocol;
                C[(size_t)r * ldc + c] = f2h(acc[i][j][q]);
            }
}

// ---------- G4 with fused weighted trace ----------
// A = T1: row m=(w,p), col kk=(lt,r): T1 + kidx*Lt8*16384 + (lt*8+w)*16384 + p*512 + r
// B = Y': row n=(v,P), col kk:        Yp + (lt*32+P)*16384 + kidx*4096 + v*512 + r
// epilogue: dacc += sum_{m,n} acc[m][n] * W2p[kidx][n*256+m]   (pref pre-folded)
__global__ __launch_bounds__(256) void gemm_g4_tr(
    const unsigned short* __restrict__ T1, const unsigned short* __restrict__ Yp,
    const float* __restrict__ W2p, float* __restrict__ dacc,
    int Lt8, int zkShift, int BKC)
{
    __shared__ short As[4096];
    __shared__ short Bs[4096];
    const int tid = threadIdx.x;
    const int wid = tid >> 6, lane = tid & 63;
    const int m0 = blockIdx.x * 128, n0 = blockIdx.y * 128;
    const int zz = blockIdx.z;
    const int kidx = zz >> zkShift;
    const int kz = (zz - (kidx << zkShift)) * BKC;
    const int wr = (wid >> 1) * 64, wc = (wid & 1) * 64;
    const int lrow = lane & 15, kb = (lane >> 4) * 8;

    const int c0 = tid, c1 = tid + 256;
    const int mA0 = m0 + (c0 >> 2), kc0 = (c0 & 3) * 8;
    const int mA1 = m0 + (c1 >> 2), kc1 = (c1 & 3) * 8;
    const int nB0 = n0 + (c0 >> 2), nB1 = n0 + (c1 >> 2);
    const int w0 = mA0 >> 5, p0 = mA0 & 31, w1 = mA1 >> 5, p1 = mA1 & 31;
    const int v0 = nB0 >> 5, P0 = nB0 & 31, v1 = nB1 >> 5, P1 = nB1 & 31;
    const size_t T1k = (size_t)kidx * Lt8 * 16384;
    const size_t Yk = (size_t)kidx * 4096;

    f32x4 acc[4][4] = {};

    for (int k0 = 0; k0 < BKC; k0 += 32) {
        const int kkA0 = kz + k0 + kc0, kkA1 = kz + k0 + kc1;
        const int lt0 = kkA0 >> 9, rr0 = kkA0 & 511;
        const int lt1 = kkA1 >> 9, rr1 = kkA1 & 511;
        gload16(T1 + T1k + (size_t)(lt0 * 8 + w0) * 16384 + p0 * 512 + rr0, (short*)As + c0 * 8);
        gload16(T1 + T1k + (size_t)(lt1 * 8 + w1) * 16384 + p1 * 512 + rr1, (short*)As + c1 * 8);
        gload16(Yp + Yk + (size_t)(lt0 * 32 + P0) * 16384 + v0 * 512 + rr0, (short*)Bs + c0 * 8);
        gload16(Yp + Yk + (size_t)(lt1 * 32 + P1) * 16384 + v1 * 512 + rr1, (short*)Bs + c1 * 8);
        __syncthreads();
        f16x8 a[4], b[4];
        #pragma unroll
        for (int i = 0; i < 4; ++i)
            a[i] = *(const f16x8*)&As[(wr + i * 16 + lrow) * 32 + kb];
        #pragma unroll
        for (int j = 0; j < 4; ++j)
            b[j] = *(const f16x8*)&Bs[(wc + j * 16 + lrow) * 32 + kb];
        #pragma unroll
        for (int i = 0; i < 4; ++i)
            #pragma unroll
            for (int j = 0; j < 4; ++j)
                acc[i][j] = __builtin_amdgcn_mfma_f32_16x16x32_f16(a[i], b[j], acc[i][j], 0, 0, 0);
        __syncthreads();
    }

    // fused weighted trace: s = sum acc[m][n] * W2p[n*256+m]
    const int orow = (lane >> 4) * 4, ocol = lane & 15;
    const float* Wk = W2p + ((size_t)kidx << 16);
    float s = 0.f;
    #pragma unroll
    for (int j = 0; j < 4; ++j) {
        const int n = n0 + wc + j * 16 + ocol;
        const float* wrow = Wk + (size_t)n * 256 + m0 + wr + orow;
        #pragma unroll
        for (int i = 0; i < 4; ++i) {
            float4 wv = *(const float4*)(wrow + i * 16);
            s += wv.x * acc[i][j][0] + wv.y * acc[i][j][1]
               + wv.z * acc[i][j][2] + wv.w * acc[i][j][3];
        }
    }
    __syncthreads();
    float* red = (float*)As;
    red[tid] = s;
    __syncthreads();
    for (int st = 128; st > 0; st >>= 1) {
        if (tid < st) red[tid] += red[tid + st];
        __syncthreads();
    }
    if (tid == 0) atomicAdd(dacc, red[0]);
}

// ---------- prep kernels ----------
// cast A to fp16 and accumulate sum(A^2)
__global__ __launch_bounds__(256) void cast_sumsq(
    const float* __restrict__ in, unsigned short* __restrict__ out,
    long long n4, float* __restrict__ sumsq)
{
    float p = 0.f;
    for (long long i = (long long)blockIdx.x * blockDim.x + threadIdx.x; i < n4;
         i += (long long)gridDim.x * blockDim.x) {
        float4 v = ((const float4*)in)[i];
        p += v.x * v.x + v.y * v.y + v.z * v.z + v.w * v.w;
        union { unsigned short s[4]; uint2 d; } o;
        o.s[0] = f2h(v.x); o.s[1] = f2h(v.y); o.s[2] = f2h(v.z); o.s[3] = f2h(v.w);
        ((uint2*)out)[i] = o.d;
    }
    __shared__ float sh[256];
    sh[threadIdx.x] = p;
    __syncthreads();
    for (int s = 128; s > 0; s >>= 1) {
        if (threadIdx.x < s) sh[threadIdx.x] += sh[threadIdx.x + s];
        __syncthreads();
    }
    if (threadIdx.x == 0) atomicAdd(sumsq, sh[0]);
}

__global__ void cast_kernel(const float* __restrict__ in, unsigned short* __restrict__ out,
                            long long n4)
{
    for (long long i = (long long)blockIdx.x * blockDim.x + threadIdx.x; i < n4;
         i += (long long)gridDim.x * blockDim.x) {
        float4 v = ((const float4*)in)[i];
        union { unsigned short s[4]; uint2 d; } o;
        o.s[0] = f2h(v.x); o.s[1] = f2h(v.y); o.s[2] = f2h(v.z); o.s[3] = f2h(v.w);
        ((uint2*)out)[i] = o.d;
    }
}

__global__ void transpose_cast(const float* __restrict__ in, unsigned short* __restrict__ out,
                               int R, int C, long long in_stride, long long out_stride)
{
    __shared__ float tile[32][33];
    in += (long long)blockIdx.z * in_stride;
    out += (long long)blockIdx.z * out_stride;
    int c0 = blockIdx.x * 32, r0 = blockIdx.y * 32;
    int tx = threadIdx.x, ty = threadIdx.y;  // (32, 8)
    #pragma unroll
    for (int i = 0; i < 4; ++i)
        tile[ty + i * 8][tx] = in[(size_t)(r0 + ty + i * 8) * C + c0 + tx];
    __syncthreads();
    #pragma unroll
    for (int i = 0; i < 4; ++i)
        out[(size_t)(c0 + ty + i * 8) * R + r0 + tx] = f2h(tile[tx][ty + i * 8]);
}

__global__ void build_ops(const float* __restrict__ theta, float* __restrict__ ops)
{
    __shared__ float X[32][32], Pm[32][32];
    int i = threadIdx.y, j = threadIdx.x;
    float c = cosf(theta[0]), s = sinf(theta[0]);
    float aij = (j == i + 1) ? sqrtf((float)j) : 0.f;
    float aji = (i == j + 1) ? sqrtf((float)i) : 0.f;
    const float inv = 0.70710678118654752440f;
    float x0 = (aij + aji) * inv;
    float p0 = (aij - aji) * inv;
    X[i][j] = c * x0 + s * p0;
    Pm[i][j] = -s * x0 + c * p0;
    __syncthreads();
    float xx = 0.f, pp = 0.f;
    #pragma unroll
    for (int m = 0; m < 32; ++m) {
        xx += X[i][m] * X[m][j];
        pp += Pm[i][m] * Pm[m][j];
    }
    ops[0 * 1024 + i * 32 + j] = (i == j) ? 1.f : 0.f;
    ops[1 * 1024 + i * 32 + j] = X[i][j];
    ops[2 * 1024 + i * 32 + j] = Pm[i][j];
    ops[3 * 1024 + i * 32 + j] = xx;
    ops[4 * 1024 + i * 32 + j] = pp;
}

// W2p[k][(v*32+P)*256 + (w*32+p)] = pref[k] * sum_c coeffs[k,w,v,c] * ops[c][P,p]
__global__ void build_w(const float* __restrict__ coeffs, const float* __restrict__ ops,
                        const float* __restrict__ pref, float* __restrict__ W2)
{
    int b = blockIdx.x;  // (k,w,v)
    int k = b >> 6, w = (b >> 3) & 7, v = b & 7;
    int P = threadIdx.y, p = threadIdx.x;
    const float* cf = coeffs + ((k * 8 + w) * 8 + v) * 5;
    float acc = 0.f;
    #pragma unroll
    for (int c = 0; c < 5; ++c) acc += cf[c] * ops[c * 1024 + P * 32 + p];
    W2[(size_t)k * 65536 + (v * 32 + P) * 256 + (w * 32 + p)] = acc * pref[k];
}

__global__ void finalize_kernel(const float* __restrict__ dacc, const float* __restrict__ sumsq,
                                float* __restrict__ out)
{
    if (threadIdx.x == 0) out[0] = dacc[0] / sumsq[0];
}

extern "C" void kernel_launch(void* const* d_in, const int* in_sizes, int n_in,
                              void* d_out, int out_size, void* d_ws, size_t ws_size,
                              hipStream_t stream)
{
    const float* A      = (const float*)d_in[0];  // [512,32,512]
    const float* theta  = (const float*)d_in[1];
    const float* envL   = (const float*)d_in[2];  // [4,512,8,512]
    const float* envR   = (const float*)d_in[3];  // [4,512,8,512]
    const float* coeffs = (const float*)d_in[4];  // [4,8,8,5]
    const float* pref   = (const float*)d_in[5];  // [4]
    float* out = (float*)d_out;

    char* ws = (char*)d_ws;
    float* sumsq = (float*)ws;                                 // 4 B
    float* dacc  = (float*)(ws + 4);                           // 4 B
    float* ops   = (float*)(ws + 64);                          // 20 KB
    float* W2    = (float*)(ws + (32 << 10));                  // 1 MB
    unsigned short* envLh  = (unsigned short*)(ws + (4ull << 20));   // 16.8 MB
    unsigned short* Ah     = (unsigned short*)(ws + (21ull << 20));  // 16.8 MB
    unsigned short* Ath    = (unsigned short*)(ws + (38ull << 20));  // 16.8 MB
    unsigned short* envRth = (unsigned short*)(ws + (55ull << 20));  // 16.8 MB
    const size_t big0 = 72ull << 20;

    // L-tile: T1 + Y' need 2*Lt MB beyond big0. Cap at 64 for L3 residency of G4 reads.
    int Lt = 64;
    while (Lt > 8) {
        size_t need = big0 + 2ull * (size_t)Lt * (1ull << 20);
        if (need <= ws_size) break;
        Lt >>= 1;
    }
    unsigned short* T1 = (unsigned short*)(ws + big0);               // [4][Lt*8][16384]
    unsigned short* Yp = T1 + (size_t)Lt * 524288;                   // [Lt*32][16384]

    const int Lt8 = Lt * 8;
    const int kshiftA = __builtin_ctz(Lt8);                          // rows per k-slab in G1
    const long long kextraA = 2097152LL - (long long)Lt8 * 512;      // skip to next envL k-slab
    const int KT = Lt * 512;
    const int BKC = (KT >= 65536) ? 1024 : 512;
    const int zk = KT / BKC;
    const int zkShift = __builtin_ctz(zk);

    hipMemsetAsync(ws, 0, 64, stream);

    cast_sumsq<<<1024, 256, 0, stream>>>(A, Ah, 2097152LL, sumsq);
    build_ops<<<1, dim3(32, 32), 0, stream>>>(theta, ops);
    build_w<<<256, dim3(32, 32), 0, stream>>>(coeffs, ops, pref, W2);
    cast_kernel<<<2048, 256, 0, stream>>>(envL, envLh, 2097152LL);
    transpose_cast<<<dim3(512, 16, 1), dim3(32, 8), 0, stream>>>(A, Ath, 512, 16384, 0, 0);
    transpose_cast<<<dim3(128, 16, 4), dim3(32, 8), 0, stream>>>(envR, envRth, 512, 4096,
                                                                 2097152LL, 2097152LL);

    const int ntiles = 512 / Lt;
    for (int t = 0; t < ntiles; ++t) {
        // G1: T1[(k,lt,w)][(p,r)] = envL(tile,all k) x At^T   [M=4*Lt*8, N=16384, K=512]
        gemm_bt2<<<dim3(128, (4 * Lt8) / 128), 256, 0, stream>>>(
            512, envLh + (size_t)t * Lt8 * 512, 512, kshiftA, kextraA,
            Ath, 512, T1, 16384);
        // G3: Y'[(lt,P)][(k,v,r)] = A(tile) x envRt(all k)^T  [M=Lt*32, N=16384, K=512]
        gemm_bt2<<<dim3(128, (Lt * 32) / 128), 256, 0, stream>>>(
            512, Ah + (size_t)t * Lt * 16384, 512, 30, 0,
            envRth, 512, Yp, 16384);
        // G4: fused-trace contraction over (lt,r) for all k
        gemm_g4_tr<<<dim3(2, 2, 4 * zk), 256, 0, stream>>>(
            T1, Yp, W2, dacc, Lt8, zkShift, BKC);
    }
    finalize_kernel<<<1, 64, 0, stream>>>(dacc, sumsq, out);
}

// Round 5
// 1288.646 us; speedup vs baseline: 8.9809x; 1.1155x over previous
//
#include <hip/hip_runtime.h>

// SingleSiteMinimizer, fp16-MFMA pipeline:
//   G1: T1[k][(lt,w)][(p,r)] = envL_k(tile) @ A     } merged into one dual-grid
//   G3: Y'[(lt,P)][k*4096+(v,r)] = A(tile) @ envR^T } dispatch (blockIdx.z)
//   G4: out += sum_k sum_{m,n} (T1_k Y'_k^T)[m,n] * W2pref[k][n][m]  (fused trace)
//   out /= sum(A^2)

typedef __attribute__((ext_vector_type(8))) _Float16 f16x8;
typedef __attribute__((ext_vector_type(4))) float f32x4;

__device__ __forceinline__ unsigned short f2h(float f) {
    _Float16 h = (_Float16)f;
    return *(unsigned short*)&h;
}

__device__ __forceinline__ void gload16(const void* g, void* l) {
    __builtin_amdgcn_global_load_lds(
        (const __attribute__((address_space(1))) void*)g,
        (__attribute__((address_space(3))) void*)l, 16, 0, 0);
}

struct GArg {
    const unsigned short* A;
    const unsigned short* B;
    unsigned short* C;
    int kshift;        // A row slab shift (30 => none)
    long long kextra;  // extra bytes-in-elems per slab
};

// ---------- dual fp16 GEMM: C[M,N] = Aop[M,K] x Bop[N,K]^T, lda=ldb=512, ldc=16384 ----------
__global__ __launch_bounds__(256) void gemm_dual(int K, GArg g0, GArg g1)
{
    __shared__ short sh[8192];  // As = sh[0:4096], Bs = sh[4096:8192]
    const GArg g = blockIdx.z ? g1 : g0;
    const int tid = threadIdx.x;
    const int wid = tid >> 6, lane = tid & 63;

    // XCD-aware swizzle over flattened (x,y); nwg multiple of 8
    const int nwg = gridDim.x * gridDim.y;
    const int cpx = nwg >> 3;
    const int flat = blockIdx.y * gridDim.x + blockIdx.x;
    const int swz = (flat & 7) * cpx + (flat >> 3);
    const int col0 = (swz % gridDim.x) * 128;
    const int row0 = (swz / gridDim.x) * 128;

    const int wr = (wid >> 1) * 64, wc = (wid & 1) * 64;
    const int lrow = lane & 15, kb = (lane >> 4) * 8;

    const int c0 = tid, c1 = tid + 256;
    const int r0 = c0 >> 2, kc0 = (c0 & 3) * 8;
    const int r1 = c1 >> 2, kc1 = (c1 & 3) * 8;
    const int gr0 = row0 + r0, gr1 = row0 + r1;
    const size_t aoff0 = (size_t)gr0 * 512 + (size_t)((unsigned)gr0 >> g.kshift) * g.kextra;
    const size_t aoff1 = (size_t)gr1 * 512 + (size_t)((unsigned)gr1 >> g.kshift) * g.kextra;
    const size_t boff0 = (size_t)(col0 + r0) * 512;
    const size_t boff1 = (size_t)(col0 + r1) * 512;

    f32x4 acc[4][4] = {};

    for (int k0 = 0; k0 < K; k0 += 32) {
        gload16(g.A + aoff0 + k0 + kc0, sh + c0 * 8);
        gload16(g.A + aoff1 + k0 + kc1, sh + c1 * 8);
        gload16(g.B + boff0 + k0 + kc0, sh + 4096 + c0 * 8);
        gload16(g.B + boff1 + k0 + kc1, sh + 4096 + c1 * 8);
        __syncthreads();
        f16x8 a[4], b[4];
        #pragma unroll
        for (int i = 0; i < 4; ++i)
            a[i] = *(const f16x8*)&sh[(wr + i * 16 + lrow) * 32 + kb];
        #pragma unroll
        for (int j = 0; j < 4; ++j)
            b[j] = *(const f16x8*)&sh[4096 + (wc + j * 16 + lrow) * 32 + kb];
        #pragma unroll
        for (int i = 0; i < 4; ++i)
            #pragma unroll
            for (int j = 0; j < 4; ++j)
                acc[i][j] = __builtin_amdgcn_mfma_f32_16x16x32_f16(a[i], b[j], acc[i][j], 0, 0, 0);
        __syncthreads();
    }

    // coalesced epilogue: repack through LDS in two 64-row halves, store int4
    const int orow = (lane >> 4) * 4, ocol = lane & 15;
    #pragma unroll
    for (int h = 0; h < 2; ++h) {
        if ((wid >> 1) == h) {
            #pragma unroll
            for (int i = 0; i < 4; ++i)
                #pragma unroll
                for (int j = 0; j < 4; ++j)
                    #pragma unroll
                    for (int q = 0; q < 4; ++q)
                        sh[(i * 16 + orow + q) * 128 + wc + j * 16 + ocol] =
                            (short)f2h(acc[i][j][q]);
        }
        __syncthreads();
        #pragma unroll
        for (int s2 = 0; s2 < 4; ++s2) {
            int idx = tid + s2 * 256;
            int rr2 = idx >> 4, ch = idx & 15;
            *(int4*)(g.C + (size_t)(row0 + h * 64 + rr2) * 16384 + col0 + ch * 8) =
                *(const int4*)(sh + rr2 * 128 + ch * 8);
        }
        __syncthreads();
    }
}

// ---------- G4: 1024-thread blocks, full 256x256 output, exactly-once reads ----------
// A = T1: row m=(w,p): T1 + kidx*Lt8*16384 + (lt*8+w)*16384 + p*512 + r
// B = Y': row n=(v,P): Yp + (lt*32+P)*16384 + kidx*4096 + v*512 + r
// epilogue: dacc += sum_{m,n} acc[m][n] * W2p[kidx][n*256+m]  (pref pre-folded)
__global__ __launch_bounds__(1024) void gemm_g4w(
    const unsigned short* __restrict__ T1, const unsigned short* __restrict__ Yp,
    const float* __restrict__ W2p, float* __restrict__ dacc,
    int Lt8, int zkShift, int BKC)
{
    __shared__ short sh[16384];  // As = sh[0:8192], Bs = sh[8192:16384]
    const int tid = threadIdx.x;
    const int wid = tid >> 6, lane = tid & 63;
    const int kidx = blockIdx.x >> zkShift;
    const int kz = (blockIdx.x - (kidx << zkShift)) * BKC;
    const int wr = (wid >> 2) * 64, wc = (wid & 3) * 64;
    const int lrow = lane & 15, kb = (lane >> 4) * 8;

    const int r = tid >> 2, kc = (tid & 3) * 8;  // staging: row 0..255
    const int w_ = r >> 5, p_ = r & 31;
    const size_t T1k = (size_t)kidx * Lt8 * 16384;
    const size_t Yk = (size_t)kidx * 4096;
    const size_t aoff = T1k + (size_t)w_ * 16384 + (size_t)p_ * 512;   // + lt*8*16384 + rr
    const size_t boff = Yk + (size_t)p_ * 16384 + (size_t)w_ * 512;    // (v=w_, P=p_)

    f32x4 acc[4][4] = {};

    for (int k0 = 0; k0 < BKC; k0 += 32) {
        const int kk = kz + k0;
        const int lt = kk >> 9, rbase = kk & 511;
        gload16(T1 + aoff + (size_t)lt * 131072 + rbase + kc, sh + tid * 8);
        gload16(Yp + boff + (size_t)lt * 524288 + rbase + kc, sh + 8192 + tid * 8);
        __syncthreads();
        f16x8 a[4], b[4];
        #pragma unroll
        for (int i = 0; i < 4; ++i)
            a[i] = *(const f16x8*)&sh[(wr + i * 16 + lrow) * 32 + kb];
        #pragma unroll
        for (int j = 0; j < 4; ++j)
            b[j] = *(const f16x8*)&sh[8192 + (wc + j * 16 + lrow) * 32 + kb];
        #pragma unroll
        for (int i = 0; i < 4; ++i)
            #pragma unroll
            for (int j = 0; j < 4; ++j)
                acc[i][j] = __builtin_amdgcn_mfma_f32_16x16x32_f16(a[i], b[j], acc[i][j], 0, 0, 0);
        __syncthreads();
    }

    // fused weighted trace
    const int orow = (lane >> 4) * 4, ocol = lane & 15;
    const float* Wk = W2p + ((size_t)kidx << 16);
    float s = 0.f;
    #pragma unroll
    for (int j = 0; j < 4; ++j) {
        const int n = wc + j * 16 + ocol;
        const float* wrow = Wk + (size_t)n * 256 + wr + orow;
        #pragma unroll
        for (int i = 0; i < 4; ++i) {
            float4 wv = *(const float4*)(wrow + i * 16);
            s += wv.x * acc[i][j][0] + wv.y * acc[i][j][1]
               + wv.z * acc[i][j][2] + wv.w * acc[i][j][3];
        }
    }
    __syncthreads();
    float* red = (float*)sh;
    red[tid] = s;
    __syncthreads();
    for (int st = 512; st > 0; st >>= 1) {
        if (tid < st) red[tid] += red[tid + st];
        __syncthreads();
    }
    if (tid == 0) atomicAdd(dacc, red[0]);
}

// ---------- prep kernels ----------
__global__ __launch_bounds__(256) void cast_sumsq(
    const float* __restrict__ in, unsigned short* __restrict__ out,
    long long n4, float* __restrict__ sumsq)
{
    float p = 0.f;
    for (long long i = (long long)blockIdx.x * blockDim.x + threadIdx.x; i < n4;
         i += (long long)gridDim.x * blockDim.x) {
        float4 v = ((const float4*)in)[i];
        p += v.x * v.x + v.y * v.y + v.z * v.z + v.w * v.w;
        union { unsigned short s[4]; uint2 d; } o;
        o.s[0] = f2h(v.x); o.s[1] = f2h(v.y); o.s[2] = f2h(v.z); o.s[3] = f2h(v.w);
        ((uint2*)out)[i] = o.d;
    }
    __shared__ float sh[256];
    sh[threadIdx.x] = p;
    __syncthreads();
    for (int s = 128; s > 0; s >>= 1) {
        if (threadIdx.x < s) sh[threadIdx.x] += sh[threadIdx.x + s];
        __syncthreads();
    }
    if (threadIdx.x == 0) atomicAdd(sumsq, sh[0]);
}

__global__ void cast_kernel(const float* __restrict__ in, unsigned short* __restrict__ out,
                            long long n4)
{
    for (long long i = (long long)blockIdx.x * blockDim.x + threadIdx.x; i < n4;
         i += (long long)gridDim.x * blockDim.x) {
        float4 v = ((const float4*)in)[i];
        union { unsigned short s[4]; uint2 d; } o;
        o.s[0] = f2h(v.x); o.s[1] = f2h(v.y); o.s[2] = f2h(v.z); o.s[3] = f2h(v.w);
        ((uint2*)out)[i] = o.d;
    }
}

__global__ void transpose_cast(const float* __restrict__ in, unsigned short* __restrict__ out,
                               int R, int C, long long in_stride, long long out_stride)
{
    __shared__ float tile[32][33];
    in += (long long)blockIdx.z * in_stride;
    out += (long long)blockIdx.z * out_stride;
    int c0 = blockIdx.x * 32, r0 = blockIdx.y * 32;
    int tx = threadIdx.x, ty = threadIdx.y;  // (32, 8)
    #pragma unroll
    for (int i = 0; i < 4; ++i)
        tile[ty + i * 8][tx] = in[(size_t)(r0 + ty + i * 8) * C + c0 + tx];
    __syncthreads();
    #pragma unroll
    for (int i = 0; i < 4; ++i)
        out[(size_t)(c0 + ty + i * 8) * R + r0 + tx] = f2h(tile[tx][ty + i * 8]);
}

__global__ void build_ops(const float* __restrict__ theta, float* __restrict__ ops)
{
    __shared__ float X[32][32], Pm[32][32];
    int i = threadIdx.y, j = threadIdx.x;
    float c = cosf(theta[0]), s = sinf(theta[0]);
    float aij = (j == i + 1) ? sqrtf((float)j) : 0.f;
    float aji = (i == j + 1) ? sqrtf((float)i) : 0.f;
    const float inv = 0.70710678118654752440f;
    float x0 = (aij + aji) * inv;
    float p0 = (aij - aji) * inv;
    X[i][j] = c * x0 + s * p0;
    Pm[i][j] = -s * x0 + c * p0;
    __syncthreads();
    float xx = 0.f, pp = 0.f;
    #pragma unroll
    for (int m = 0; m < 32; ++m) {
        xx += X[i][m] * X[m][j];
        pp += Pm[i][m] * Pm[m][j];
    }
    ops[0 * 1024 + i * 32 + j] = (i == j) ? 1.f : 0.f;
    ops[1 * 1024 + i * 32 + j] = X[i][j];
    ops[2 * 1024 + i * 32 + j] = Pm[i][j];
    ops[3 * 1024 + i * 32 + j] = xx;
    ops[4 * 1024 + i * 32 + j] = pp;
}

// W2p[k][(v*32+P)*256 + (w*32+p)] = pref[k] * sum_c coeffs[k,w,v,c] * ops[c][P,p]
__global__ void build_w(const float* __restrict__ coeffs, const float* __restrict__ ops,
                        const float* __restrict__ pref, float* __restrict__ W2)
{
    int b = blockIdx.x;  // (k,w,v)
    int k = b >> 6, w = (b >> 3) & 7, v = b & 7;
    int P = threadIdx.y, p = threadIdx.x;
    const float* cf = coeffs + ((k * 8 + w) * 8 + v) * 5;
    float acc = 0.f;
    #pragma unroll
    for (int c = 0; c < 5; ++c) acc += cf[c] * ops[c * 1024 + P * 32 + p];
    W2[(size_t)k * 65536 + (v * 32 + P) * 256 + (w * 32 + p)] = acc * pref[k];
}

__global__ void finalize_kernel(const float* __restrict__ dacc, const float* __restrict__ sumsq,
                                float* __restrict__ out)
{
    if (threadIdx.x == 0) out[0] = dacc[0] / sumsq[0];
}

extern "C" void kernel_launch(void* const* d_in, const int* in_sizes, int n_in,
                              void* d_out, int out_size, void* d_ws, size_t ws_size,
                              hipStream_t stream)
{
    const float* A      = (const float*)d_in[0];  // [512,32,512]
    const float* theta  = (const float*)d_in[1];
    const float* envL   = (const float*)d_in[2];  // [4,512,8,512]
    const float* envR   = (const float*)d_in[3];  // [4,512,8,512]
    const float* coeffs = (const float*)d_in[4];  // [4,8,8,5]
    const float* pref   = (const float*)d_in[5];  // [4]
    float* out = (float*)d_out;

    char* ws = (char*)d_ws;
    float* sumsq = (float*)ws;                                 // 4 B
    float* dacc  = (float*)(ws + 4);                           // 4 B
    float* ops   = (float*)(ws + 64);                          // 20 KB
    float* W2    = (float*)(ws + (32 << 10));                  // 1 MB
    unsigned short* envLh  = (unsigned short*)(ws + (4ull << 20));   // 16.8 MB
    unsigned short* Ah     = (unsigned short*)(ws + (21ull << 20));  // 16.8 MB
    unsigned short* Ath    = (unsigned short*)(ws + (38ull << 20));  // 16.8 MB
    unsigned short* envRth = (unsigned short*)(ws + (55ull << 20));  // 16.8 MB
    const size_t big0 = 72ull << 20;

    int Lt = 64;
    while (Lt > 8) {
        size_t need = big0 + 2ull * (size_t)Lt * (1ull << 20);
        if (need <= ws_size) break;
        Lt >>= 1;
    }
    unsigned short* T1 = (unsigned short*)(ws + big0);               // [4][Lt*8][16384]
    unsigned short* Yp = T1 + (size_t)Lt * 524288;                   // [Lt*32][16384]

    const int Lt8 = Lt * 8;
    const int kshiftA = __builtin_ctz(Lt8);                          // G1 k-slab shift
    const long long kextraA = 2097152LL - (long long)Lt8 * 512;
    const int KT = Lt * 512;
    int BKC = KT / 64; if (BKC < 128) BKC = 128;
    const int zk = KT / BKC;
    const int zkShift = __builtin_ctz(zk);

    hipMemsetAsync(ws, 0, 64, stream);

    cast_sumsq<<<1024, 256, 0, stream>>>(A, Ah, 2097152LL, sumsq);
    build_ops<<<1, dim3(32, 32), 0, stream>>>(theta, ops);
    build_w<<<256, dim3(32, 32), 0, stream>>>(coeffs, ops, pref, W2);
    cast_kernel<<<2048, 256, 0, stream>>>(envL, envLh, 2097152LL);
    transpose_cast<<<dim3(512, 16, 1), dim3(32, 8), 0, stream>>>(A, Ath, 512, 16384, 0, 0);
    transpose_cast<<<dim3(128, 16, 4), dim3(32, 8), 0, stream>>>(envR, envRth, 512, 4096,
                                                                 2097152LL, 2097152LL);

    const int ntiles = 512 / Lt;
    for (int t = 0; t < ntiles; ++t) {
        GArg g0, g1;
        // G1: T1[(k,lt,w)][(p,r)] = envL(tile,all k) x Ath^T  [M=4*Lt8, N=16384, K=512]
        g0.A = envLh + (size_t)t * Lt8 * 512; g0.B = Ath; g0.C = T1;
        g0.kshift = kshiftA; g0.kextra = kextraA;
        // G3: Y'[(lt,P)][(k,v,r)] = A(tile) x envRth^T        [M=Lt*32, N=16384, K=512]
        g1.A = Ah + (size_t)t * Lt * 16384; g1.B = envRth; g1.C = Yp;
        g1.kshift = 30; g1.kextra = 0;
        gemm_dual<<<dim3(128, (Lt * 32) / 128, 2), 256, 0, stream>>>(512, g0, g1);
        // G4: fused-trace contraction over (lt,r), all k
        gemm_g4w<<<dim3(4 * zk), 1024, 0, stream>>>(T1, Yp, W2, dacc, Lt8, zkShift, BKC);
    }
    finalize_kernel<<<1, 64, 0, stream>>>(dacc, sumsq, out);
}

// Round 6
// 1206.461 us; speedup vs baseline: 9.5927x; 1.0681x over previous
//
#include <hip/hip_runtime.h>

// SingleSiteMinimizer, fp16-MFMA pipeline:
//   G1: T1[k][(lt,w)][(p,r)] = envL_k(tile) @ A     } merged into one dual-grid
//   G3: Y'[(lt,P)][k*4096+(v,r)] = A(tile) @ envR^T } dispatch (blockIdx.z)
//   G4: out += sum_k sum_{m,n} (T1_k Y'_k^T)[m,n] * W2pref[k][n][m]  (fused trace)
//   out /= sum(A^2)
// Round 6: XCD-pinned B-column-panel block mapping (L2 residency of the 16.8 MB
// B operand: 2.1 MB/XCD hot-set) + bank-conflict-free padded epilogue repack.

typedef __attribute__((ext_vector_type(8))) _Float16 f16x8;
typedef __attribute__((ext_vector_type(4))) float f32x4;

#define EPS 136  // epilogue LDS row stride in shorts (272 B -> +4 banks per row)

__device__ __forceinline__ unsigned short f2h(float f) {
    _Float16 h = (_Float16)f;
    return *(unsigned short*)&h;
}

__device__ __forceinline__ void gload16(const void* g, void* l) {
    __builtin_amdgcn_global_load_lds(
        (const __attribute__((address_space(1))) void*)g,
        (__attribute__((address_space(3))) void*)l, 16, 0, 0);
}

struct GArg {
    const unsigned short* A;
    const unsigned short* B;
    unsigned short* C;
    int kshift;        // A row slab shift (30 => none)
    long long kextra;  // extra elems per slab
};

// ---------- dual fp16 GEMM: C[M,N] = Aop[M,K] x Bop[N,K]^T, lda=ldb=512, ldc=16384 ----------
// gridDim.x MUST be 128 (col panels); col panels pinned per-XCD for L2 reuse.
__global__ __launch_bounds__(256) void gemm_dual(int K, GArg g0, GArg g1)
{
    __shared__ short sh[8704];  // main loop: As=sh[0:4096], Bs=sh[4096:8192]; epilogue: 64xEPS
    const GArg g = blockIdx.z ? g1 : g0;
    const int tid = threadIdx.x;
    const int wid = tid >> 6, lane = tid & 63;

    // XCD-pinned mapping: xcd owns 16 consecutive col panels; iterates cols fast.
    const int flat = blockIdx.y * 128 + blockIdx.x;
    const int xcd = flat & 7;
    const int local = flat >> 3;
    const int col0 = (xcd * 16 + (local & 15)) * 128;
    const int row0 = (local >> 4) * 128;

    const int wr = (wid >> 1) * 64, wc = (wid & 1) * 64;
    const int lrow = lane & 15, kb = (lane >> 4) * 8;

    const int c0 = tid, c1 = tid + 256;
    const int r0 = c0 >> 2, kc0 = (c0 & 3) * 8;
    const int r1 = c1 >> 2, kc1 = (c1 & 3) * 8;
    const int gr0 = row0 + r0, gr1 = row0 + r1;
    const size_t aoff0 = (size_t)gr0 * 512 + (size_t)((unsigned)gr0 >> g.kshift) * g.kextra;
    const size_t aoff1 = (size_t)gr1 * 512 + (size_t)((unsigned)gr1 >> g.kshift) * g.kextra;
    const size_t boff0 = (size_t)(col0 + r0) * 512;
    const size_t boff1 = (size_t)(col0 + r1) * 512;

    f32x4 acc[4][4] = {};

    for (int k0 = 0; k0 < K; k0 += 32) {
        gload16(g.A + aoff0 + k0 + kc0, sh + c0 * 8);
        gload16(g.A + aoff1 + k0 + kc1, sh + c1 * 8);
        gload16(g.B + boff0 + k0 + kc0, sh + 4096 + c0 * 8);
        gload16(g.B + boff1 + k0 + kc1, sh + 4096 + c1 * 8);
        __syncthreads();
        f16x8 a[4], b[4];
        #pragma unroll
        for (int i = 0; i < 4; ++i)
            a[i] = *(const f16x8*)&sh[(wr + i * 16 + lrow) * 32 + kb];
        #pragma unroll
        for (int j = 0; j < 4; ++j)
            b[j] = *(const f16x8*)&sh[4096 + (wc + j * 16 + lrow) * 32 + kb];
        #pragma unroll
        for (int i = 0; i < 4; ++i)
            #pragma unroll
            for (int j = 0; j < 4; ++j)
                acc[i][j] = __builtin_amdgcn_mfma_f32_16x16x32_f16(a[i], b[j], acc[i][j], 0, 0, 0);
        __syncthreads();
    }

    // coalesced epilogue: repack through LDS in two 64-row halves, store int4
    const int orow = (lane >> 4) * 4, ocol = lane & 15;
    #pragma unroll
    for (int h = 0; h < 2; ++h) {
        if ((wid >> 1) == h) {
            #pragma unroll
            for (int i = 0; i < 4; ++i)
                #pragma unroll
                for (int j = 0; j < 4; ++j)
                    #pragma unroll
                    for (int q = 0; q < 4; ++q)
                        sh[(i * 16 + orow + q) * EPS + wc + j * 16 + ocol] =
                            (short)f2h(acc[i][j][q]);
        }
        __syncthreads();
        #pragma unroll
        for (int s2 = 0; s2 < 4; ++s2) {
            int idx = tid + s2 * 256;
            int rr2 = idx >> 4, ch = idx & 15;
            *(int4*)(g.C + (size_t)(row0 + h * 64 + rr2) * 16384 + col0 + ch * 8) =
                *(const int4*)(sh + rr2 * EPS + ch * 8);
        }
        __syncthreads();
    }
}

// ---------- G4: 1024-thread blocks, full 256x256 output, exactly-once reads ----------
__global__ __launch_bounds__(1024) void gemm_g4w(
    const unsigned short* __restrict__ T1, const unsigned short* __restrict__ Yp,
    const float* __restrict__ W2p, float* __restrict__ dacc,
    int Lt8, int zkShift, int BKC)
{
    __shared__ short sh[16384];  // As = sh[0:8192], Bs = sh[8192:16384]
    const int tid = threadIdx.x;
    const int wid = tid >> 6, lane = tid & 63;
    const int kidx = blockIdx.x >> zkShift;
    const int kz = (blockIdx.x - (kidx << zkShift)) * BKC;
    const int wr = (wid >> 2) * 64, wc = (wid & 3) * 64;
    const int lrow = lane & 15, kb = (lane >> 4) * 8;

    const int r = tid >> 2, kc = (tid & 3) * 8;  // staging: row 0..255
    const int w_ = r >> 5, p_ = r & 31;
    const size_t T1k = (size_t)kidx * Lt8 * 16384;
    const size_t Yk = (size_t)kidx * 4096;
    const size_t aoff = T1k + (size_t)w_ * 16384 + (size_t)p_ * 512;   // + lt*131072 + rr
    const size_t boff = Yk + (size_t)p_ * 16384 + (size_t)w_ * 512;    // (v=w_, P=p_)

    f32x4 acc[4][4] = {};

    for (int k0 = 0; k0 < BKC; k0 += 32) {
        const int kk = kz + k0;
        const int lt = kk >> 9, rbase = kk & 511;
        gload16(T1 + aoff + (size_t)lt * 131072 + rbase + kc, sh + tid * 8);
        gload16(Yp + boff + (size_t)lt * 524288 + rbase + kc, sh + 8192 + tid * 8);
        __syncthreads();
        f16x8 a[4], b[4];
        #pragma unroll
        for (int i = 0; i < 4; ++i)
            a[i] = *(const f16x8*)&sh[(wr + i * 16 + lrow) * 32 + kb];
        #pragma unroll
        for (int j = 0; j < 4; ++j)
            b[j] = *(const f16x8*)&sh[8192 + (wc + j * 16 + lrow) * 32 + kb];
        #pragma unroll
        for (int i = 0; i < 4; ++i)
            #pragma unroll
            for (int j = 0; j < 4; ++j)
                acc[i][j] = __builtin_amdgcn_mfma_f32_16x16x32_f16(a[i], b[j], acc[i][j], 0, 0, 0);
        __syncthreads();
    }

    // fused weighted trace
    const int orow = (lane >> 4) * 4, ocol = lane & 15;
    const float* Wk = W2p + ((size_t)kidx << 16);
    float s = 0.f;
    #pragma unroll
    for (int j = 0; j < 4; ++j) {
        const int n = wc + j * 16 + ocol;
        const float* wrow = Wk + (size_t)n * 256 + wr + orow;
        #pragma unroll
        for (int i = 0; i < 4; ++i) {
            float4 wv = *(const float4*)(wrow + i * 16);
            s += wv.x * acc[i][j][0] + wv.y * acc[i][j][1]
               + wv.z * acc[i][j][2] + wv.w * acc[i][j][3];
        }
    }
    __syncthreads();
    float* red = (float*)sh;
    red[tid] = s;
    __syncthreads();
    for (int st = 512; st > 0; st >>= 1) {
        if (tid < st) red[tid] += red[tid + st];
        __syncthreads();
    }
    if (tid == 0) atomicAdd(dacc, red[0]);
}

// ---------- prep kernels ----------
__global__ __launch_bounds__(256) void cast_sumsq(
    const float* __restrict__ in, unsigned short* __restrict__ out,
    long long n4, float* __restrict__ sumsq)
{
    float p = 0.f;
    for (long long i = (long long)blockIdx.x * blockDim.x + threadIdx.x; i < n4;
         i += (long long)gridDim.x * blockDim.x) {
        float4 v = ((const float4*)in)[i];
        p += v.x * v.x + v.y * v.y + v.z * v.z + v.w * v.w;
        union { unsigned short s[4]; uint2 d; } o;
        o.s[0] = f2h(v.x); o.s[1] = f2h(v.y); o.s[2] = f2h(v.z); o.s[3] = f2h(v.w);
        ((uint2*)out)[i] = o.d;
    }
    __shared__ float sh[256];
    sh[threadIdx.x] = p;
    __syncthreads();
    for (int s = 128; s > 0; s >>= 1) {
        if (threadIdx.x < s) sh[threadIdx.x] += sh[threadIdx.x + s];
        __syncthreads();
    }
    if (threadIdx.x == 0) atomicAdd(sumsq, sh[0]);
}

__global__ void cast_kernel(const float* __restrict__ in, unsigned short* __restrict__ out,
                            long long n4)
{
    for (long long i = (long long)blockIdx.x * blockDim.x + threadIdx.x; i < n4;
         i += (long long)gridDim.x * blockDim.x) {
        float4 v = ((const float4*)in)[i];
        union { unsigned short s[4]; uint2 d; } o;
        o.s[0] = f2h(v.x); o.s[1] = f2h(v.y); o.s[2] = f2h(v.z); o.s[3] = f2h(v.w);
        ((uint2*)out)[i] = o.d;
    }
}

__global__ void transpose_cast(const float* __restrict__ in, unsigned short* __restrict__ out,
                               int R, int C, long long in_stride, long long out_stride)
{
    __shared__ float tile[32][33];
    in += (long long)blockIdx.z * in_stride;
    out += (long long)blockIdx.z * out_stride;
    int c0 = blockIdx.x * 32, r0 = blockIdx.y * 32;
    int tx = threadIdx.x, ty = threadIdx.y;  // (32, 8)
    #pragma unroll
    for (int i = 0; i < 4; ++i)
        tile[ty + i * 8][tx] = in[(size_t)(r0 + ty + i * 8) * C + c0 + tx];
    __syncthreads();
    #pragma unroll
    for (int i = 0; i < 4; ++i)
        out[(size_t)(c0 + ty + i * 8) * R + r0 + tx] = f2h(tile[tx][ty + i * 8]);
}

__global__ void build_ops(const float* __restrict__ theta, float* __restrict__ ops)
{
    __shared__ float X[32][32], Pm[32][32];
    int i = threadIdx.y, j = threadIdx.x;
    float c = cosf(theta[0]), s = sinf(theta[0]);
    float aij = (j == i + 1) ? sqrtf((float)j) : 0.f;
    float aji = (i == j + 1) ? sqrtf((float)i) : 0.f;
    const float inv = 0.70710678118654752440f;
    float x0 = (aij + aji) * inv;
    float p0 = (aij - aji) * inv;
    X[i][j] = c * x0 + s * p0;
    Pm[i][j] = -s * x0 + c * p0;
    __syncthreads();
    float xx = 0.f, pp = 0.f;
    #pragma unroll
    for (int m = 0; m < 32; ++m) {
        xx += X[i][m] * X[m][j];
        pp += Pm[i][m] * Pm[m][j];
    }
    ops[0 * 1024 + i * 32 + j] = (i == j) ? 1.f : 0.f;
    ops[1 * 1024 + i * 32 + j] = X[i][j];
    ops[2 * 1024 + i * 32 + j] = Pm[i][j];
    ops[3 * 1024 + i * 32 + j] = xx;
    ops[4 * 1024 + i * 32 + j] = pp;
}

// W2p[k][(v*32+P)*256 + (w*32+p)] = pref[k] * sum_c coeffs[k,w,v,c] * ops[c][P,p]
__global__ void build_w(const float* __restrict__ coeffs, const float* __restrict__ ops,
                        const float* __restrict__ pref, float* __restrict__ W2)
{
    int b = blockIdx.x;  // (k,w,v)
    int k = b >> 6, w = (b >> 3) & 7, v = b & 7;
    int P = threadIdx.y, p = threadIdx.x;
    const float* cf = coeffs + ((k * 8 + w) * 8 + v) * 5;
    float acc = 0.f;
    #pragma unroll
    for (int c = 0; c < 5; ++c) acc += cf[c] * ops[c * 1024 + P * 32 + p];
    W2[(size_t)k * 65536 + (v * 32 + P) * 256 + (w * 32 + p)] = acc * pref[k];
}

__global__ void finalize_kernel(const float* __restrict__ dacc, const float* __restrict__ sumsq,
                                float* __restrict__ out)
{
    if (threadIdx.x == 0) out[0] = dacc[0] / sumsq[0];
}

extern "C" void kernel_launch(void* const* d_in, const int* in_sizes, int n_in,
                              void* d_out, int out_size, void* d_ws, size_t ws_size,
                              hipStream_t stream)
{
    const float* A      = (const float*)d_in[0];  // [512,32,512]
    const float* theta  = (const float*)d_in[1];
    const float* envL   = (const float*)d_in[2];  // [4,512,8,512]
    const float* envR   = (const float*)d_in[3];  // [4,512,8,512]
    const float* coeffs = (const float*)d_in[4];  // [4,8,8,5]
    const float* pref   = (const float*)d_in[5];  // [4]
    float* out = (float*)d_out;

    char* ws = (char*)d_ws;
    float* sumsq = (float*)ws;                                 // 4 B
    float* dacc  = (float*)(ws + 4);                           // 4 B
    float* ops   = (float*)(ws + 64);                          // 20 KB
    float* W2    = (float*)(ws + (32 << 10));                  // 1 MB
    unsigned short* envLh  = (unsigned short*)(ws + (4ull << 20));   // 16.8 MB
    unsigned short* Ah     = (unsigned short*)(ws + (21ull << 20));  // 16.8 MB
    unsigned short* Ath    = (unsigned short*)(ws + (38ull << 20));  // 16.8 MB
    unsigned short* envRth = (unsigned short*)(ws + (55ull << 20));  // 16.8 MB
    const size_t big0 = 72ull << 20;

    int Lt = 64;
    while (Lt > 8) {
        size_t need = big0 + 2ull * (size_t)Lt * (1ull << 20);
        if (need <= ws_size) break;
        Lt >>= 1;
    }
    unsigned short* T1 = (unsigned short*)(ws + big0);               // [4][Lt*8][16384]
    unsigned short* Yp = T1 + (size_t)Lt * 524288;                   // [Lt*32][16384]

    const int Lt8 = Lt * 8;
    const int kshiftA = __builtin_ctz(Lt8);                          // G1 k-slab shift
    const long long kextraA = 2097152LL - (long long)Lt8 * 512;
    const int KT = Lt * 512;
    int BKC = KT / 64; if (BKC < 128) BKC = 128;
    const int zk = KT / BKC;
    const int zkShift = __builtin_ctz(zk);

    hipMemsetAsync(ws, 0, 64, stream);

    cast_sumsq<<<1024, 256, 0, stream>>>(A, Ah, 2097152LL, sumsq);
    build_ops<<<1, dim3(32, 32), 0, stream>>>(theta, ops);
    build_w<<<256, dim3(32, 32), 0, stream>>>(coeffs, ops, pref, W2);
    cast_kernel<<<2048, 256, 0, stream>>>(envL, envLh, 2097152LL);
    transpose_cast<<<dim3(512, 16, 1), dim3(32, 8), 0, stream>>>(A, Ath, 512, 16384, 0, 0);
    transpose_cast<<<dim3(128, 16, 4), dim3(32, 8), 0, stream>>>(envR, envRth, 512, 4096,
                                                                 2097152LL, 2097152LL);

    const int ntiles = 512 / Lt;
    for (int t = 0; t < ntiles; ++t) {
        GArg g0, g1;
        // G1: T1[(k,lt,w)][(p,r)] = envL(tile,all k) x Ath^T  [M=4*Lt8, N=16384, K=512]
        g0.A = envLh + (size_t)t * Lt8 * 512; g0.B = Ath; g0.C = T1;
        g0.kshift = kshiftA; g0.kextra = kextraA;
        // G3: Y'[(lt,P)][(k,v,r)] = A(tile) x envRth^T        [M=Lt*32, N=16384, K=512]
        g1.A = Ah + (size_t)t * Lt * 16384; g1.B = envRth; g1.C = Yp;
        g1.kshift = 30; g1.kextra = 0;
        gemm_dual<<<dim3(128, (Lt * 32) / 128, 2), 256, 0, stream>>>(512, g0, g1);
        // G4: fused-trace contraction over (lt,r), all k
        gemm_g4w<<<dim3(4 * zk), 1024, 0, stream>>>(T1, Yp, W2, dacc, Lt8, zkShift, BKC);
    }
    finalize_kernel<<<1, 64, 0, stream>>>(dacc, sumsq, out);
}

// Round 7
// 1041.531 us; speedup vs baseline: 11.1117x; 1.1584x over previous
//
#include <hip/hip_runtime.h>

// SingleSiteMinimizer, fp16-MFMA pipeline:
//   G1: T1[k][(lt,w)][(p,r)] = envL_k(tile) @ A     } merged dual-grid dispatch
//   G3: Y'[(lt,P)][k*4096+(v,r)] = A(tile) @ envR^T } (blockIdx.z)
//   G4: out += sum_k sum_{m,n} (T1_k Y'_k^T)[m,n] * W2pref[k][n][m]  (fused trace)
//   out /= sum(A^2)
// Round 7: 256x256/BK=64 counted-vmcnt pipeline (T2 swizzle + T4 counted waits +
// T5 setprio), 512 threads, 128 KB LDS double-buffer, XCD-pinned col panels.

typedef __attribute__((ext_vector_type(8))) _Float16 f16x8;
typedef __attribute__((ext_vector_type(4))) float f32x4;

__device__ __forceinline__ unsigned short f2h(float f) {
    _Float16 h = (_Float16)f;
    return *(unsigned short*)&h;
}

__device__ __forceinline__ void gload16(const void* g, void* l) {
    __builtin_amdgcn_global_load_lds(
        (const __attribute__((address_space(1))) void*)g,
        (__attribute__((address_space(3))) void*)l, 16, 0, 0);
}

struct GArg {
    const unsigned short* A;
    const unsigned short* B;
    unsigned short* C;
    int kshift;        // A row slab shift (30 => none)
    long long kextra;  // extra elems per slab
};

// Stage one 256x64 fp16 K-tile of A and B into linear LDS with inverse-swizzled
// global source: LDS slot (r, g) holds global k-chunk g^(r&7)  [rule 21].
// LDS dest = uniform_base + lane*16 (c = q*512 + tid is lane-contiguous).
__device__ __forceinline__ void stage_tile(
    const GArg& g, int row0, int col0, int kt0,
    short* dstA, short* dstB, int tid)
{
    #pragma unroll
    for (int q = 0; q < 4; ++q) {
        const int c = q * 512 + tid;
        const int r = c >> 3;
        const int gs = (c & 7) ^ (r & 7);
        const int gr = row0 + r;
        const size_t aoff = (size_t)gr * 512 + (size_t)((unsigned)gr >> g.kshift) * g.kextra;
        gload16(g.A + aoff + kt0 + gs * 8, dstA + c * 8);
        gload16(g.B + (size_t)(col0 + r) * 512 + kt0 + gs * 8, dstB + c * 8);
    }
}

// ---------- 256x256 dual fp16 GEMM: C[M,N] = Aop[M,K] x Bop[N,K]^T ----------
// lda=ldb=512, ldc=16384. gridDim.x MUST be 64 (col panels), XCD-pinned.
__global__ __launch_bounds__(512, 2) void gemm_dual256(int K, GArg g0, GArg g1)
{
    __shared__ short lds[65536];  // 128 KB: A0,B0,A1,B1 (16384 shorts each)
    const GArg g = blockIdx.z ? g1 : g0;
    const int tid = threadIdx.x;
    const int wid = tid >> 6, lane = tid & 63;
    const int wm = wid >> 2, wn = wid & 3;          // 2M x 4N waves
    const int lrow = lane & 15, lgrp = lane >> 4;
    const int sx = lrow & 7;                        // read-side swizzle xor
    const int gsw0 = (lgrp ^ sx) * 8, gsw1 = ((lgrp + 4) ^ sx) * 8;

    // XCD-pinned mapping: xcd owns 8 consecutive col panels (2 MB L2 hot-set)
    const int flat = blockIdx.y * 64 + blockIdx.x;
    const int xcd = flat & 7, local = flat >> 3;
    const int col0 = (xcd * 8 + (local & 7)) * 256;
    const int row0 = (local >> 3) * 256;

    const int nt = K >> 6;                          // K-tiles of 64 (= 8)
    short* A0 = lds;          short* B0 = lds + 16384;
    short* A1 = lds + 32768;  short* B1 = lds + 49152;

    f32x4 acc[8][4] = {};

    stage_tile(g, row0, col0, 0, A0, B0, tid);
    stage_tile(g, row0, col0, 64, A1, B1, tid);
    asm volatile("s_waitcnt vmcnt(8)" ::: "memory");   // tile 0 landed; tile 1 in flight
    __builtin_amdgcn_s_barrier();
    __builtin_amdgcn_sched_barrier(0);

    for (int t = 0; t < nt; ++t) {
        const short* cA = (t & 1) ? A1 : A0;
        const short* cB = (t & 1) ? B1 : B0;
        short* wA = (t & 1) ? A1 : A0;
        short* wB = (t & 1) ? B1 : B0;

        f16x8 bfr[4][2], afr[4][2];
        #pragma unroll
        for (int j = 0; j < 4; ++j) {
            const int R = wn * 64 + j * 16 + lrow;
            bfr[j][0] = *(const f16x8*)&cB[R * 64 + gsw0];
            bfr[j][1] = *(const f16x8*)&cB[R * 64 + gsw1];
        }
        #pragma unroll
        for (int i = 0; i < 4; ++i) {
            const int R = wm * 128 + i * 16 + lrow;
            afr[i][0] = *(const f16x8*)&cA[R * 64 + gsw0];
            afr[i][1] = *(const f16x8*)&cA[R * 64 + gsw1];
        }
        __builtin_amdgcn_s_setprio(1);
        #pragma unroll
        for (int i = 0; i < 4; ++i)
            #pragma unroll
            for (int j = 0; j < 4; ++j) {
                acc[i][j] = __builtin_amdgcn_mfma_f32_16x16x32_f16(afr[i][0], bfr[j][0], acc[i][j], 0, 0, 0);
                acc[i][j] = __builtin_amdgcn_mfma_f32_16x16x32_f16(afr[i][1], bfr[j][1], acc[i][j], 0, 0, 0);
            }
        __builtin_amdgcn_s_setprio(0);
        // phase-2 A fragments (rows 64..127 of the wave's M-half)
        #pragma unroll
        for (int i = 0; i < 4; ++i) {
            const int R = wm * 128 + (i + 4) * 16 + lrow;
            afr[i][0] = *(const f16x8*)&cA[R * 64 + gsw0];
            afr[i][1] = *(const f16x8*)&cA[R * 64 + gsw1];
        }
        asm volatile("s_waitcnt lgkmcnt(0)" ::: "memory");
        __builtin_amdgcn_sched_barrier(0);
        __builtin_amdgcn_s_barrier();               // all reads of buf[t&1] retired
        __builtin_amdgcn_sched_barrier(0);
        if (t + 2 < nt)
            stage_tile(g, row0, col0, (t + 2) * 64, wA, wB, tid);  // overwrite read buffer
        __builtin_amdgcn_s_setprio(1);
        #pragma unroll
        for (int i = 0; i < 4; ++i)
            #pragma unroll
            for (int j = 0; j < 4; ++j) {
                acc[i + 4][j] = __builtin_amdgcn_mfma_f32_16x16x32_f16(afr[i][0], bfr[j][0], acc[i + 4][j], 0, 0, 0);
                acc[i + 4][j] = __builtin_amdgcn_mfma_f32_16x16x32_f16(afr[i][1], bfr[j][1], acc[i + 4][j], 0, 0, 0);
            }
        __builtin_amdgcn_s_setprio(0);
        if (t < nt - 1) {
            if (t + 2 < nt) asm volatile("s_waitcnt vmcnt(8)" ::: "memory");  // t+1 done, t+2 in flight
            else            asm volatile("s_waitcnt vmcnt(0)" ::: "memory");  // tail drain
            __builtin_amdgcn_sched_barrier(0);
            __builtin_amdgcn_s_barrier();
            __builtin_amdgcn_sched_barrier(0);
        }
    }

    // epilogue: repack through LDS (stride 264 shorts: 16B-aligned, 2-way-free banks)
    const int orow = lgrp * 4, ocol = lrow;
    __syncthreads();
    #pragma unroll
    for (int h = 0; h < 2; ++h) {
        if (wm == h) {
            #pragma unroll
            for (int i = 0; i < 8; ++i)
                #pragma unroll
                for (int j = 0; j < 4; ++j)
                    #pragma unroll
                    for (int q = 0; q < 4; ++q)
                        lds[(i * 16 + orow + q) * 264 + wn * 64 + j * 16 + ocol] =
                            (short)f2h(acc[i][j][q]);
        }
        __syncthreads();
        #pragma unroll
        for (int s2 = 0; s2 < 8; ++s2) {
            const int ch = s2 * 512 + tid;
            const int rr = ch >> 5, c16 = ch & 31;
            *(int4*)(g.C + (size_t)(row0 + h * 128 + rr) * 16384 + col0 + c16 * 8) =
                *(const int4*)&lds[rr * 264 + c16 * 8];
        }
        __syncthreads();
    }
}

// ---------- G4: 1024-thread blocks, full 256x256 output, exactly-once reads ----------
__global__ __launch_bounds__(1024) void gemm_g4w(
    const unsigned short* __restrict__ T1, const unsigned short* __restrict__ Yp,
    const float* __restrict__ W2p, float* __restrict__ dacc,
    int Lt8, int zkShift, int BKC)
{
    __shared__ short sh[16384];  // As = sh[0:8192], Bs = sh[8192:16384]
    const int tid = threadIdx.x;
    const int wid = tid >> 6, lane = tid & 63;
    const int kidx = blockIdx.x >> zkShift;
    const int kz = (blockIdx.x - (kidx << zkShift)) * BKC;
    const int wr = (wid >> 2) * 64, wc = (wid & 3) * 64;
    const int lrow = lane & 15, kb = (lane >> 4) * 8;

    const int r = tid >> 2, kc = (tid & 3) * 8;  // staging: row 0..255
    const int w_ = r >> 5, p_ = r & 31;
    const size_t T1k = (size_t)kidx * Lt8 * 16384;
    const size_t Yk = (size_t)kidx * 4096;
    const size_t aoff = T1k + (size_t)w_ * 16384 + (size_t)p_ * 512;   // + lt*131072 + rr
    const size_t boff = Yk + (size_t)p_ * 16384 + (size_t)w_ * 512;    // (v=w_, P=p_)

    f32x4 acc[4][4] = {};

    for (int k0 = 0; k0 < BKC; k0 += 32) {
        const int kk = kz + k0;
        const int lt = kk >> 9, rbase = kk & 511;
        gload16(T1 + aoff + (size_t)lt * 131072 + rbase + kc, sh + tid * 8);
        gload16(Yp + boff + (size_t)lt * 524288 + rbase + kc, sh + 8192 + tid * 8);
        __syncthreads();
        f16x8 a[4], b[4];
        #pragma unroll
        for (int i = 0; i < 4; ++i)
            a[i] = *(const f16x8*)&sh[(wr + i * 16 + lrow) * 32 + kb];
        #pragma unroll
        for (int j = 0; j < 4; ++j)
            b[j] = *(const f16x8*)&sh[8192 + (wc + j * 16 + lrow) * 32 + kb];
        #pragma unroll
        for (int i = 0; i < 4; ++i)
            #pragma unroll
            for (int j = 0; j < 4; ++j)
                acc[i][j] = __builtin_amdgcn_mfma_f32_16x16x32_f16(a[i], b[j], acc[i][j], 0, 0, 0);
        __syncthreads();
    }

    // fused weighted trace
    const int orow = (lane >> 4) * 4, ocol = lane & 15;
    const float* Wk = W2p + ((size_t)kidx << 16);
    float s = 0.f;
    #pragma unroll
    for (int j = 0; j < 4; ++j) {
        const int n = wc + j * 16 + ocol;
        const float* wrow = Wk + (size_t)n * 256 + wr + orow;
        #pragma unroll
        for (int i = 0; i < 4; ++i) {
            float4 wv = *(const float4*)(wrow + i * 16);
            s += wv.x * acc[i][j][0] + wv.y * acc[i][j][1]
               + wv.z * acc[i][j][2] + wv.w * acc[i][j][3];
        }
    }
    __syncthreads();
    float* red = (float*)sh;
    red[tid] = s;
    __syncthreads();
    for (int st = 512; st > 0; st >>= 1) {
        if (tid < st) red[tid] += red[tid + st];
        __syncthreads();
    }
    if (tid == 0) atomicAdd(dacc, red[0]);
}

// ---------- prep kernels ----------
__global__ __launch_bounds__(256) void cast_sumsq(
    const float* __restrict__ in, unsigned short* __restrict__ out,
    long long n4, float* __restrict__ sumsq)
{
    float p = 0.f;
    for (long long i = (long long)blockIdx.x * blockDim.x + threadIdx.x; i < n4;
         i += (long long)gridDim.x * blockDim.x) {
        float4 v = ((const float4*)in)[i];
        p += v.x * v.x + v.y * v.y + v.z * v.z + v.w * v.w;
        union { unsigned short s[4]; uint2 d; } o;
        o.s[0] = f2h(v.x); o.s[1] = f2h(v.y); o.s[2] = f2h(v.z); o.s[3] = f2h(v.w);
        ((uint2*)out)[i] = o.d;
    }
    __shared__ float sh[256];
    sh[threadIdx.x] = p;
    __syncthreads();
    for (int s = 128; s > 0; s >>= 1) {
        if (threadIdx.x < s) sh[threadIdx.x] += sh[threadIdx.x + s];
        __syncthreads();
    }
    if (threadIdx.x == 0) atomicAdd(sumsq, sh[0]);
}

__global__ void cast_kernel(const float* __restrict__ in, unsigned short* __restrict__ out,
                            long long n4)
{
    for (long long i = (long long)blockIdx.x * blockDim.x + threadIdx.x; i < n4;
         i += (long long)gridDim.x * blockDim.x) {
        float4 v = ((const float4*)in)[i];
        union { unsigned short s[4]; uint2 d; } o;
        o.s[0] = f2h(v.x); o.s[1] = f2h(v.y); o.s[2] = f2h(v.z); o.s[3] = f2h(v.w);
        ((uint2*)out)[i] = o.d;
    }
}

__global__ void transpose_cast(const float* __restrict__ in, unsigned short* __restrict__ out,
                               int R, int C, long long in_stride, long long out_stride)
{
    __shared__ float tile[32][33];
    in += (long long)blockIdx.z * in_stride;
    out += (long long)blockIdx.z * out_stride;
    int c0 = blockIdx.x * 32, r0 = blockIdx.y * 32;
    int tx = threadIdx.x, ty = threadIdx.y;  // (32, 8)
    #pragma unroll
    for (int i = 0; i < 4; ++i)
        tile[ty + i * 8][tx] = in[(size_t)(r0 + ty + i * 8) * C + c0 + tx];
    __syncthreads();
    #pragma unroll
    for (int i = 0; i < 4; ++i)
        out[(size_t)(c0 + ty + i * 8) * R + r0 + tx] = f2h(tile[tx][ty + i * 8]);
}

__global__ void build_ops(const float* __restrict__ theta, float* __restrict__ ops)
{
    __shared__ float X[32][32], Pm[32][32];
    int i = threadIdx.y, j = threadIdx.x;
    float c = cosf(theta[0]), s = sinf(theta[0]);
    float aij = (j == i + 1) ? sqrtf((float)j) : 0.f;
    float aji = (i == j + 1) ? sqrtf((float)i) : 0.f;
    const float inv = 0.70710678118654752440f;
    float x0 = (aij + aji) * inv;
    float p0 = (aij - aji) * inv;
    X[i][j] = c * x0 + s * p0;
    Pm[i][j] = -s * x0 + c * p0;
    __syncthreads();
    float xx = 0.f, pp = 0.f;
    #pragma unroll
    for (int m = 0; m < 32; ++m) {
        xx += X[i][m] * X[m][j];
        pp += Pm[i][m] * Pm[m][j];
    }
    ops[0 * 1024 + i * 32 + j] = (i == j) ? 1.f : 0.f;
    ops[1 * 1024 + i * 32 + j] = X[i][j];
    ops[2 * 1024 + i * 32 + j] = Pm[i][j];
    ops[3 * 1024 + i * 32 + j] = xx;
    ops[4 * 1024 + i * 32 + j] = pp;
}

// W2p[k][(v*32+P)*256 + (w*32+p)] = pref[k] * sum_c coeffs[k,w,v,c] * ops[c][P,p]
__global__ void build_w(const float* __restrict__ coeffs, const float* __restrict__ ops,
                        const float* __restrict__ pref, float* __restrict__ W2)
{
    int b = blockIdx.x;  // (k,w,v)
    int k = b >> 6, w = (b >> 3) & 7, v = b & 7;
    int P = threadIdx.y, p = threadIdx.x;
    const float* cf = coeffs + ((k * 8 + w) * 8 + v) * 5;
    float acc = 0.f;
    #pragma unroll
    for (int c = 0; c < 5; ++c) acc += cf[c] * ops[c * 1024 + P * 32 + p];
    W2[(size_t)k * 65536 + (v * 32 + P) * 256 + (w * 32 + p)] = acc * pref[k];
}

__global__ void finalize_kernel(const float* __restrict__ dacc, const float* __restrict__ sumsq,
                                float* __restrict__ out)
{
    if (threadIdx.x == 0) out[0] = dacc[0] / sumsq[0];
}

extern "C" void kernel_launch(void* const* d_in, const int* in_sizes, int n_in,
                              void* d_out, int out_size, void* d_ws, size_t ws_size,
                              hipStream_t stream)
{
    const float* A      = (const float*)d_in[0];  // [512,32,512]
    const float* theta  = (const float*)d_in[1];
    const float* envL   = (const float*)d_in[2];  // [4,512,8,512]
    const float* envR   = (const float*)d_in[3];  // [4,512,8,512]
    const float* coeffs = (const float*)d_in[4];  // [4,8,8,5]
    const float* pref   = (const float*)d_in[5];  // [4]
    float* out = (float*)d_out;

    char* ws = (char*)d_ws;
    float* sumsq = (float*)ws;                                 // 4 B
    float* dacc  = (float*)(ws + 4);                           // 4 B
    float* ops   = (float*)(ws + 64);                          // 20 KB
    float* W2    = (float*)(ws + (32 << 10));                  // 1 MB
    unsigned short* envLh  = (unsigned short*)(ws + (4ull << 20));   // 16.8 MB
    unsigned short* Ah     = (unsigned short*)(ws + (21ull << 20));  // 16.8 MB
    unsigned short* Ath    = (unsigned short*)(ws + (38ull << 20));  // 16.8 MB
    unsigned short* envRth = (unsigned short*)(ws + (55ull << 20));  // 16.8 MB
    const size_t big0 = 72ull << 20;

    int Lt = 64;
    while (Lt > 8) {
        size_t need = big0 + 2ull * (size_t)Lt * (1ull << 20);
        if (need <= ws_size) break;
        Lt >>= 1;
    }
    unsigned short* T1 = (unsigned short*)(ws + big0);               // [4][Lt*8][16384]
    unsigned short* Yp = T1 + (size_t)Lt * 524288;                   // [Lt*32][16384]

    const int Lt8 = Lt * 8;
    const int kshiftA = __builtin_ctz(Lt8);                          // G1 k-slab shift
    const long long kextraA = 2097152LL - (long long)Lt8 * 512;
    const int KT = Lt * 512;
    int BKC = KT / 64; if (BKC < 128) BKC = 128;
    const int zk = KT / BKC;
    const int zkShift = __builtin_ctz(zk);

    hipMemsetAsync(ws, 0, 64, stream);

    cast_sumsq<<<1024, 256, 0, stream>>>(A, Ah, 2097152LL, sumsq);
    build_ops<<<1, dim3(32, 32), 0, stream>>>(theta, ops);
    build_w<<<256, dim3(32, 32), 0, stream>>>(coeffs, ops, pref, W2);
    cast_kernel<<<2048, 256, 0, stream>>>(envL, envLh, 2097152LL);
    transpose_cast<<<dim3(512, 16, 1), dim3(32, 8), 0, stream>>>(A, Ath, 512, 16384, 0, 0);
    transpose_cast<<<dim3(128, 16, 4), dim3(32, 8), 0, stream>>>(envR, envRth, 512, 4096,
                                                                 2097152LL, 2097152LL);

    const int ntiles = 512 / Lt;
    for (int t = 0; t < ntiles; ++t) {
        GArg g0, g1;
        // G1: T1[(k,lt,w)][(p,r)] = envL(tile,all k) x Ath^T  [M=4*Lt8, N=16384, K=512]
        g0.A = envLh + (size_t)t * Lt8 * 512; g0.B = Ath; g0.C = T1;
        g0.kshift = kshiftA; g0.kextra = kextraA;
        // G3: Y'[(lt,P)][(k,v,r)] = A(tile) x envRth^T        [M=Lt*32, N=16384, K=512]
        g1.A = Ah + (size_t)t * Lt * 16384; g1.B = envRth; g1.C = Yp;
        g1.kshift = 30; g1.kextra = 0;
        gemm_dual256<<<dim3(64, (Lt * 32) / 256, 2), 512, 0, stream>>>(512, g0, g1);
        // G4: fused-trace contraction over (lt,r), all k
        gemm_g4w<<<dim3(4 * zk), 1024, 0, stream>>>(T1, Yp, W2, dacc, Lt8, zkShift, BKC);
    }
    finalize_kernel<<<1, 64, 0, stream>>>(dacc, sumsq, out);
}